// Round 16
// baseline (515.819 us; speedup 1.0000x reference)
//
#include <hip/hip_runtime.h>
#include <cstdint>

typedef __bf16 bf16;
typedef __attribute__((ext_vector_type(4))) __bf16 bf16x4;
typedef __attribute__((ext_vector_type(8))) __bf16 bf16x8;
typedef __attribute__((ext_vector_type(4))) float f32x4;

#define DEVI __device__ __forceinline__

#define BATCH 2
#define SEQ 2048
#define HID 4096
#define NH 32
#define NKVH 8
#define HD 128
#define QKVN 6144
#define MROWS 4096
#define ATT_SCALE 0.08838834764831845f
#define QSCALE (0.08838834764831845f * 1.4426950408889634f)
#define ROPE_C (-0.2076205059304601f)   // -log2(10000)/64

DEVI void gload_lds16(const bf16* g, bf16* l) {
  __builtin_amdgcn_global_load_lds(
      (__attribute__((address_space(1))) void*)(g),
      (__attribute__((address_space(3))) void*)(l), 16, 0, 0);
}

// ---------------- elementwise f32 -> bf16 ----------------
__global__ void h2b_kernel(const float* __restrict__ in, bf16* __restrict__ out) {
  long i = ((long)blockIdx.x * 256 + threadIdx.x) * 4;
  float4 v = *(const float4*)(in + i);
  bf16x4 o;
  o[0] = (bf16)v.x; o[1] = (bf16)v.y; o[2] = (bf16)v.z; o[3] = (bf16)v.w;
  *(bf16x4*)(out + i) = o;
}

// ---------------- transpose-convert weight v1 (proven R11): (K,N) f32 -> (N,K) bf16 ----
__global__ void wtrans_kernel(const float* __restrict__ in, bf16* __restrict__ out,
                              int K, int N) {
  __shared__ float t[64][65];
  int n0 = blockIdx.x * 64, k0 = blockIdx.y * 64;
  int tid = threadIdx.x;
  int tx = tid & 15, ty = tid >> 4;   // 16 x 16
#pragma unroll
  for (int rr = 0; rr < 4; ++rr) {
    int k = ty * 4 + rr;
    float4 v = *(const float4*)(in + (long)(k0 + k) * N + n0 + tx * 4);
    t[k][tx * 4 + 0] = v.x; t[k][tx * 4 + 1] = v.y;
    t[k][tx * 4 + 2] = v.z; t[k][tx * 4 + 3] = v.w;
  }
  __syncthreads();
  int kc = tid & 7, nn = tid >> 3;    // 8 k-chunks x 32 n-rows
#pragma unroll
  for (int pp = 0; pp < 2; ++pp) {
    int n = nn + pp * 32;
    bf16x8 o;
#pragma unroll
    for (int j = 0; j < 8; ++j) o[j] = (bf16)t[kc * 8 + j][n];
    *(bf16x8*)(out + (long)(n0 + n) * K + k0 + kc * 8) = o;
  }
}

// ---------------- RoPE in-place, K columns ONLY (Q fused into attn) ----------------
__global__ void ropek_kernel(bf16* __restrict__ qkv, const int* __restrict__ pos) {
  long t = (long)blockIdx.x * 256 + threadIdx.x;   // MROWS*8*8 threads
  int d8 = (int)(t & 7) * 8;
  long u = t >> 3;
  int hh = (int)(u % 8);
  int row = (int)(u / 8);
  float p = (float)pos[row];
  bf16* base = qkv + (long)row * QKVN + 4096 + hh * HD + d8;
  bf16x8 x1v = *(const bf16x8*)(base);
  bf16x8 x2v = *(const bf16x8*)(base + 64);
  bf16x8 o1, o2;
#pragma unroll
  for (int j = 0; j < 8; ++j) {
    float ang = p * exp2f((float)(d8 + j) * ROPE_C);
    float sn, cs;
    __sincosf(ang, &sn, &cs);
    float x1 = (float)x1v[j], x2 = (float)x2v[j];
    o1[j] = (bf16)(x1 * cs - x2 * sn);
    o2[j] = (bf16)(x2 * cs + x1 * sn);
  }
  *(bf16x8*)(base) = o1;
  *(bf16x8*)(base + 64) = o2;
}

// ---------------- transpose V: qkv v-cols -> vt (b,kvh,D,S) ----------------
__global__ void vtrans_kernel(const bf16* __restrict__ qkv, bf16* __restrict__ vt) {
  __shared__ bf16 t[32][33];
  int s0 = blockIdx.x * 32, d0 = blockIdx.y * 32, bk = blockIdx.z;
  int b = bk >> 3, kvh = bk & 7;
  int tx = threadIdx.x, ty = threadIdx.y; // (32,8)
#pragma unroll
  for (int r = 0; r < 4; ++r) {
    int s = ty + r * 8;
    t[s][tx] = qkv[(long)(b * SEQ + s0 + s) * QKVN + 5120 + kvh * HD + d0 + tx];
  }
  __syncthreads();
#pragma unroll
  for (int r = 0; r < 4; ++r) {
    int d = ty + r * 8;
    vt[((long)bk * HD + d0 + d) * SEQ + s0 + tx] = t[tx][d];
  }
}

// ---------------- ring-3 GEMM (proven, GEMM1): C = A x BT^T ----------------
template <typename OutT>
__global__ __launch_bounds__(512, 2)
void gemm256(const bf16* __restrict__ A, const bf16* __restrict__ BT,
             OutT* __restrict__ C, int M, int N, int K) {
  extern __shared__ __align__(16) bf16 lds[];
  const int tid = threadIdx.x;
  const int lane = tid & 63, wave = tid >> 6;
  const int wm = wave >> 1, wn = wave & 1;
  const int l16 = lane & 15, lhi = lane >> 4;
  const int nwg = gridDim.x * gridDim.y;
  const int bid = blockIdx.y * gridDim.x + blockIdx.x;
  const int cpx = nwg >> 3;
  const int swz = (bid & 7) * cpx + (bid >> 3);
  const int bx = swz % gridDim.x, by = swz / gridDim.x;
  const long bm0 = (long)by * 256, bn0 = (long)bx * 128;

  const int srow8 = lane >> 3;
  const int scol = (lane & 7) ^ srow8;

  const int NT = K >> 6;
  f32x4 acc[4][4] = {};

  auto stage = [&](int slot, int t) {
    const long k0 = (long)t << 6;
    bf16* dst = lds + slot * 24576;
#pragma unroll
    for (int i = 0; i < 4; ++i) {
      int r = (wave * 4 + i) * 8 + srow8;
      gload_lds16(A + (bm0 + r) * K + k0 + scol * 8,
                  dst + (wave * 4 + i) * 512 + lane * 8);
    }
#pragma unroll
    for (int i = 0; i < 2; ++i) {
      int r = (wave * 2 + i) * 8 + srow8;
      gload_lds16(BT + (bn0 + r) * K + k0 + scol * 8,
                  dst + 16384 + (wave * 2 + i) * 512 + lane * 8);
    }
  };

  stage(0, 0);
  stage(1, 1);

  for (int t = 0; t < NT; ++t) {
    asm volatile("s_waitcnt vmcnt(6)" ::: "memory");
    __builtin_amdgcn_s_barrier();
    __builtin_amdgcn_sched_barrier(0);
    const int nxt = (t + 2 < NT) ? t + 2 : NT - 1;
    stage((t + 2) % 3, nxt);
    const bf16* As = lds + (t % 3) * 24576;
    const bf16* Bs = As + 16384;
#pragma unroll
    for (int kk = 0; kk < 2; ++kk) {
      bf16x8 af[4], bw[4];
#pragma unroll
      for (int i = 0; i < 4; ++i) {
        int ar = wm * 64 + i * 16 + l16;
        af[i] = *(const bf16x8*)(As + ar * 64 + (((kk * 4 + lhi) ^ (ar & 7))) * 8);
        int br = wn * 64 + i * 16 + l16;
        bw[i] = *(const bf16x8*)(Bs + br * 64 + (((kk * 4 + lhi) ^ (br & 7))) * 8);
      }
      __builtin_amdgcn_s_setprio(1);
#pragma unroll
      for (int i = 0; i < 4; ++i)
#pragma unroll
        for (int j = 0; j < 4; ++j)
          acc[i][j] = __builtin_amdgcn_mfma_f32_16x16x32_bf16(af[i], bw[j], acc[i][j], 0, 0, 0);
      __builtin_amdgcn_s_setprio(0);
    }
  }
  asm volatile("s_waitcnt vmcnt(0)" ::: "memory");
#pragma unroll
  for (int i = 0; i < 4; ++i)
#pragma unroll
    for (int r = 0; r < 4; ++r) {
      long grow = bm0 + wm * 64 + i * 16 + lhi * 4 + r;
#pragma unroll
      for (int j = 0; j < 4; ++j) {
        long gcol = bn0 + wn * 64 + j * 16 + l16;
        C[grow * N + gcol] = (OutT)acc[i][j][r];
      }
    }
}

// ---------------- 8-phase GEMM v3 (GEMM2): balanced reads 12/12/0/0 ----------------
// 256x256 tile, BK=64, 8 waves (2M x 4N). All current-tile LDS data is landed at
// tile entry (end-of-tile vmcnt(6)), so ALL ds_reads go in ph0 (a0+b0) and ph1
// (a1+b1); phases 2/3 are pure-register MFMA overlapping the t+2 stage issues.
// Stages: ph1 A-hi(t+1) [opp parity], ph2 A-lo(t+2)+B-lo(t+2), ph3 B-hi(t+2)
// (all four halves' reads complete by ph1-end barrier -> WAR-safe).
// FIFO at end-of-tile vmcnt(6): 14 outstanding, drains 8 oldest = all t+1 halves.
template <typename OutT>
__global__ __launch_bounds__(512, 2)
void gemm8p(const bf16* __restrict__ A, const bf16* __restrict__ BT,
            OutT* __restrict__ C, int M, int N, int K) {
  extern __shared__ __align__(16) bf16 lds[];
  const int tid = threadIdx.x;
  const int lane = tid & 63, wave = tid >> 6;
  const int wm = wave >> 2, wn = wave & 3;   // 2M x 4N
  const int l16 = lane & 15, lhi = lane >> 4;
  const int nwg = gridDim.x * gridDim.y;
  const int bid = blockIdx.y * gridDim.x + blockIdx.x;
  const int cpx = nwg >> 3;
  const int swz = (bid & 7) * cpx + (bid >> 3);
  const int bx = swz % gridDim.x, by = swz / gridDim.x;
  const long bm0 = (long)by * 256, bn0 = (long)bx * 256;

  bf16* Alds = lds;              // [2 buf][2 half][128][64]
  bf16* Blds = lds + 32768;
  const int NT = K >> 6;

  f32x4 acc[8][4] = {};

  auto stageH = [&](const bf16* src, long row0, long k0, bf16* dst) {
#pragma unroll
    for (int j = 0; j < 2; ++j) {
      int r = j * 64 + (tid >> 3);
      int sc = (tid & 7) ^ (r & 7);
      gload_lds16(src + (row0 + r) * (long)K + k0 + sc * 8,
                  dst + j * 4096 + tid * 8);
    }
  };

  // prologue: tile0 all 4 halves + tile1 {A-lo, B-lo, B-hi} = 14 loads
  stageH(A, bm0, 0, Alds);
  stageH(A, bm0 + 128, 0, Alds + 8192);
  stageH(BT, bn0, 0, Blds);
  stageH(BT, bn0 + 128, 0, Blds + 8192);
  {
    long k1p = (NT > 1) ? 64 : 0;
    stageH(A, bm0, k1p, Alds + 16384);
    stageH(BT, bn0, k1p, Blds + 16384);
    stageH(BT, bn0 + 128, k1p, Blds + 24576);
  }
  asm volatile("s_waitcnt vmcnt(6)" ::: "memory");
  __builtin_amdgcn_s_barrier();

  const int arow0 = wm * 128 + l16;
  const int brow0 = wn * 64 + l16;

  for (int t = 0; t < NT; ++t) {
    const bf16* Ab = Alds + (t & 1) * 16384;
    const bf16* Bb = Blds + (t & 1) * 16384;
    bf16* Aopp = Alds + ((t + 1) & 1) * 16384;
    bf16* Asame = Alds + (t & 1) * 16384;   // (t+2) parity == t parity
    bf16* Bsame = Blds + (t & 1) * 16384;
    const long k1 = (long)((t + 1 < NT) ? t + 1 : NT - 1) << 6;
    const long k2 = (long)((t + 2 < NT) ? t + 2 : NT - 1) << 6;

    bf16x8 a0[4][2], a1[4][2], b0[2][2], b1[2][2];
    // ---- phase 0: reads a0 (8) + b0 (4); MFMA q(mh0,np0)
#pragma unroll
    for (int i = 0; i < 4; ++i) {
      int mr = arow0 + i * 16;
#pragma unroll
      for (int kk = 0; kk < 2; ++kk)
        a0[i][kk] = *(const bf16x8*)(Ab + mr * 64 + (((kk * 4 + lhi) ^ (mr & 7))) * 8);
    }
#pragma unroll
    for (int n = 0; n < 2; ++n) {
      int br = brow0 + n * 16;
#pragma unroll
      for (int kk = 0; kk < 2; ++kk)
        b0[n][kk] = *(const bf16x8*)(Bb + br * 64 + (((kk * 4 + lhi) ^ (br & 7))) * 8);
    }
    __builtin_amdgcn_s_barrier();
    asm volatile("s_waitcnt lgkmcnt(0)" ::: "memory");
    __builtin_amdgcn_sched_barrier(0);
    __builtin_amdgcn_s_setprio(1);
#pragma unroll
    for (int i = 0; i < 4; ++i)
#pragma unroll
      for (int n = 0; n < 2; ++n)
#pragma unroll
        for (int kk = 0; kk < 2; ++kk)
          acc[i][n] = __builtin_amdgcn_mfma_f32_16x16x32_bf16(a0[i][kk], b0[n][kk], acc[i][n], 0, 0, 0);
    __builtin_amdgcn_s_setprio(0);
    __builtin_amdgcn_s_barrier();
    // ---- phase 1: reads a1 (8) + b1 (4); stage A-hi(t+1); MFMA q(mh1,np0)
#pragma unroll
    for (int i = 0; i < 4; ++i) {
      int mr = arow0 + 64 + i * 16;
#pragma unroll
      for (int kk = 0; kk < 2; ++kk)
        a1[i][kk] = *(const bf16x8*)(Ab + mr * 64 + (((kk * 4 + lhi) ^ (mr & 7))) * 8);
    }
#pragma unroll
    for (int n = 0; n < 2; ++n) {
      int br = brow0 + (n + 2) * 16;
#pragma unroll
      for (int kk = 0; kk < 2; ++kk)
        b1[n][kk] = *(const bf16x8*)(Bb + br * 64 + (((kk * 4 + lhi) ^ (br & 7))) * 8);
    }
    stageH(A, bm0 + 128, k1, Aopp + 8192);
    __builtin_amdgcn_s_barrier();
    asm volatile("s_waitcnt lgkmcnt(0)" ::: "memory");
    __builtin_amdgcn_sched_barrier(0);
    __builtin_amdgcn_s_setprio(1);
#pragma unroll
    for (int i = 0; i < 4; ++i)
#pragma unroll
      for (int n = 0; n < 2; ++n)
#pragma unroll
        for (int kk = 0; kk < 2; ++kk)
          acc[4 + i][n] = __builtin_amdgcn_mfma_f32_16x16x32_bf16(a1[i][kk], b0[n][kk], acc[4 + i][n], 0, 0, 0);
    __builtin_amdgcn_s_setprio(0);
    __builtin_amdgcn_s_barrier();
    // ---- phase 2: pure-reg MFMA q(mh1,np1); stage A-lo(t+2) + B-lo(t+2)
    stageH(A, bm0, k2, Asame);
    stageH(BT, bn0, k2, Bsame);
    __builtin_amdgcn_s_barrier();
    __builtin_amdgcn_s_setprio(1);
#pragma unroll
    for (int i = 0; i < 4; ++i)
#pragma unroll
      for (int n = 0; n < 2; ++n)
#pragma unroll
        for (int kk = 0; kk < 2; ++kk)
          acc[4 + i][n + 2] = __builtin_amdgcn_mfma_f32_16x16x32_bf16(a1[i][kk], b1[n][kk], acc[4 + i][n + 2], 0, 0, 0);
    __builtin_amdgcn_s_setprio(0);
    __builtin_amdgcn_s_barrier();
    // ---- phase 3: pure-reg MFMA q(mh0,np1); stage B-hi(t+2); vmcnt(6)
    stageH(BT, bn0 + 128, k2, Bsame + 8192);
    __builtin_amdgcn_s_barrier();
    __builtin_amdgcn_s_setprio(1);
#pragma unroll
    for (int i = 0; i < 4; ++i)
#pragma unroll
      for (int n = 0; n < 2; ++n)
#pragma unroll
        for (int kk = 0; kk < 2; ++kk)
          acc[i][n + 2] = __builtin_amdgcn_mfma_f32_16x16x32_bf16(a0[i][kk], b1[n][kk], acc[i][n + 2], 0, 0, 0);
    __builtin_amdgcn_s_setprio(0);
    asm volatile("s_waitcnt vmcnt(6)" ::: "memory");  // tile t+1 fully landed
    __builtin_amdgcn_s_barrier();
  }
  asm volatile("s_waitcnt vmcnt(0)" ::: "memory");
#pragma unroll
  for (int mi = 0; mi < 8; ++mi)
#pragma unroll
    for (int r = 0; r < 4; ++r) {
      long grow = bm0 + wm * 128 + mi * 16 + lhi * 4 + r;
#pragma unroll
      for (int n = 0; n < 4; ++n) {
        long gcol = bn0 + wn * 64 + n * 16 + l16;
        C[grow * N + gcol] = (OutT)acc[mi][n][r];
      }
    }
}

// ---------------- flash attention: balanced pairs + counted-vmcnt (proven) ----------------
__global__ __launch_bounds__(512, 4)
void attn_kernel(const bf16* __restrict__ qkv, const bf16* __restrict__ vt,
                 const int* __restrict__ pos, bf16* __restrict__ out) {
  extern __shared__ __align__(16) bf16 smem[];
  const int pi = blockIdx.x, h = blockIdx.y, b = blockIdx.z;
  const int kvh = h >> 2;
  const int tid = threadIdx.x, lane = tid & 63, wave = tid >> 6;
  const int l16 = lane & 15, lhi = lane >> 4;
  const int kloc = lhi * 4;
  bf16* Pw = smem + 32768 + wave * 1024;

  const bf16* kpan = qkv + (long)(b * SEQ) * QKVN + 4096 + kvh * HD;
  const bf16* vpan = vt + (long)(b * NKVH + kvh) * HD * SEQ;

  auto stageKV = [&](int buf, int step) {   // exactly 4 gload_lds per lane
    const int kv0 = step * 64;
    bf16* kd = smem + buf * 8192;
    bf16* vd = smem + 16384 + buf * 8192;
#pragma unroll
    for (int i = 0; i < 2; ++i) {
      int kr = wave * 8 + i * 4 + lhi;
      gload_lds16(kpan + (long)(kv0 + kr) * QKVN + (l16 ^ (kr & 7)) * 8,
                  kd + (wave * 8 + i * 4) * 128);
      int vr = wave * 16 + i * 8 + (lane >> 3);
      gload_lds16(vpan + (long)vr * SEQ + kv0 + ((lane & 7) ^ (vr & 7)) * 8,
                  vd + (wave * 16 + i * 8) * 64);
    }
  };

  auto process_chunk = [&](int q0, int nsteps) {
    const int qrow = q0 + wave * 16 + l16;
    float p = (float)pos[b * SEQ + qrow];
    const bf16* qb = qkv + (long)(b * SEQ + qrow) * QKVN + h * HD + lhi * 8;
    bf16x8 raw[4];
#pragma unroll
    for (int di = 0; di < 4; ++di) raw[di] = *(const bf16x8*)(qb + di * 32);
    bf16x8 qf[4];
#pragma unroll
    for (int pr = 0; pr < 2; ++pr)
#pragma unroll
      for (int j = 0; j < 8; ++j) {
        int d = lhi * 8 + pr * 32 + j;
        float ang = p * exp2f((float)d * ROPE_C);
        float sn, cs;
        __sincosf(ang, &sn, &cs);
        float x1 = (float)raw[pr][j], x2 = (float)raw[pr + 2][j];
        qf[pr][j] = (bf16)((x1 * cs - x2 * sn) * QSCALE);
        qf[pr + 2][j] = (bf16)((x2 * cs + x1 * sn) * QSCALE);
      }

    f32x4 oacc[8] = {};
    float m_run = -1e30f, l_run = 0.f;
    const int qg = qrow;
    const int qwmin = q0 + wave * 16;

    stageKV(0, 0);
    asm volatile("s_waitcnt vmcnt(0)" ::: "memory");
    __builtin_amdgcn_s_barrier();

    for (int step = 0; step < nsteps; ++step) {
      const int kv0 = step * 64;
      const int cur = step & 1;
      if (step + 1 < nsteps) {
        stageKV(cur ^ 1, step + 1);
        asm volatile("s_waitcnt vmcnt(4)" ::: "memory");
      } else {
        asm volatile("s_waitcnt vmcnt(0)" ::: "memory");
      }
      const bf16* Kc = smem + cur * 8192;
      const bf16* Vc = smem + 16384 + cur * 8192;

      f32x4 s[4];
      __builtin_amdgcn_s_setprio(1);
#pragma unroll
      for (int c = 0; c < 4; ++c) {
        s[c] = (f32x4){0.f, 0.f, 0.f, 0.f};
        int kr = c * 16 + l16;
#pragma unroll
        for (int di = 0; di < 4; ++di) {
          bf16x8 kf = *(const bf16x8*)(Kc + kr * 128 + (((di * 4 + lhi) ^ (kr & 7))) * 8);
          s[c] = __builtin_amdgcn_mfma_f32_16x16x32_bf16(kf, qf[di], s[c], 0, 0, 0);
        }
      }
      __builtin_amdgcn_s_setprio(0);
      if (kv0 + 63 > qwmin) {
#pragma unroll
        for (int c = 0; c < 4; ++c)
#pragma unroll
          for (int r = 0; r < 4; ++r) {
            int kcol = kv0 + c * 16 + kloc + r;
            if (kcol > qg) s[c][r] = -1e30f;
          }
      }
      float mloc = s[0][0];
#pragma unroll
      for (int c = 0; c < 4; ++c)
#pragma unroll
        for (int r = 0; r < 4; ++r) mloc = fmaxf(mloc, s[c][r]);
      mloc = fmaxf(mloc, __shfl_xor(mloc, 16, 64));
      mloc = fmaxf(mloc, __shfl_xor(mloc, 32, 64));
      bool skip = __all(mloc - m_run <= 8.0f);
      float alpha = 1.f;
      if (!skip) {
        float mn = fmaxf(m_run, mloc);
        alpha = exp2f(m_run - mn);
        m_run = mn;
      }
      float sm = 0.f;
      bf16x4 pb[4];
#pragma unroll
      for (int c = 0; c < 4; ++c)
#pragma unroll
        for (int r = 0; r < 4; ++r) {
          float pv = exp2f(s[c][r] - m_run);
          sm += pv;
          pb[c][r] = (bf16)pv;
        }
      sm += __shfl_xor(sm, 16, 64);
      sm += __shfl_xor(sm, 32, 64);
      l_run = l_run * alpha + sm;
#pragma unroll
      for (int c = 0; c < 4; ++c) {
        int sl = (c * 2 + (lhi >> 1)) ^ (l16 & 7);
        *(bf16x4*)(Pw + l16 * 64 + sl * 8 + (lhi & 1) * 4) = pb[c];
      }
      if (!skip) {
        float a_o[4];
#pragma unroll
        for (int r = 0; r < 4; ++r) a_o[r] = __shfl(alpha, kloc + r, 64);
#pragma unroll
        for (int dj = 0; dj < 8; ++dj)
#pragma unroll
          for (int r = 0; r < 4; ++r) oacc[dj][r] *= a_o[r];
      }
      __builtin_amdgcn_s_setprio(1);
#pragma unroll
      for (int kh = 0; kh < 2; ++kh) {
        bf16x8 pf = *(const bf16x8*)(Pw + l16 * 64 + (((kh * 4 + lhi) ^ (l16 & 7))) * 8);
#pragma unroll
        for (int dj = 0; dj < 8; ++dj) {
          int vr = dj * 16 + l16;
          bf16x8 vf = *(const bf16x8*)(Vc + vr * 64 + (((kh * 4 + lhi) ^ (vr & 7))) * 8);
          oacc[dj] = __builtin_amdgcn_mfma_f32_16x16x32_bf16(pf, vf, oacc[dj], 0, 0, 0);
        }
      }
      __builtin_amdgcn_s_setprio(0);
      __builtin_amdgcn_s_barrier();
    }
    float linv[4];
#pragma unroll
    for (int r = 0; r < 4; ++r) linv[r] = 1.f / __shfl(l_run, kloc + r, 64);
#pragma unroll
    for (int r = 0; r < 4; ++r) {
      long orow = (long)(b * SEQ + q0 + wave * 16 + lhi * 4 + r);
#pragma unroll
      for (int dj = 0; dj < 8; ++dj)
        out[orow * (NH * HD) + h * HD + dj * 16 + l16] = (bf16)(oacc[dj][r] * linv[r]);
    }
  };

  process_chunk(pi * 128, 2 * pi + 2);
  process_chunk((15 - pi) * 128, 32 - 2 * pi);
}

extern "C" void kernel_launch(void* const* d_in, const int* in_sizes, int n_in,
                              void* d_out, int out_size, void* d_ws, size_t ws_size,
                              hipStream_t stream) {
  const int* positions = (const int*)d_in[0];
  const float* hidden = (const float*)d_in[1];
  const float* wq = (const float*)d_in[2];
  const float* wk = (const float*)d_in[3];
  const float* wv = (const float*)d_in[4];
  const float* wo = (const float*)d_in[5];
  float* out = (float*)d_out;
  char* ws = (char*)d_ws;

  const size_t SZ_H = (size_t)MROWS * HID * 2;
  const size_t SZ_WQKV = (size_t)QKVN * HID * 2;
  const size_t SZ_WO = (size_t)HID * HID * 2;
  bf16* h_bf = (bf16*)(ws);
  bf16* wqkvT = (bf16*)(ws + SZ_H);
  bf16* woT = (bf16*)(ws + SZ_H + SZ_WQKV);
  bf16* qkv = (bf16*)(ws + SZ_H + SZ_WQKV + SZ_WO);
  bf16* attn = h_bf;
  bf16* vtbuf = wqkvT;

  const int G8P_SMEM = 131072;
  const int R3_SMEM = 3 * 24576 * 2;
  const int ATTN_SMEM = 40960 * 2;
  auto* g1 = gemm256<bf16>;
  auto* g2 = gemm8p<float>;
  hipFuncSetAttribute(reinterpret_cast<const void*>(g1),
                      hipFuncAttributeMaxDynamicSharedMemorySize, R3_SMEM);
  hipFuncSetAttribute(reinterpret_cast<const void*>(g2),
                      hipFuncAttributeMaxDynamicSharedMemorySize, G8P_SMEM);
  hipFuncSetAttribute(reinterpret_cast<const void*>(attn_kernel),
                      hipFuncAttributeMaxDynamicSharedMemorySize, ATTN_SMEM);

  h2b_kernel<<<(MROWS * (long)HID) / (256 * 4), 256, 0, stream>>>(hidden, h_bf);
  wtrans_kernel<<<dim3(HID / 64, HID / 64), 256, 0, stream>>>(wq, wqkvT, HID, HID);
  wtrans_kernel<<<dim3(1024 / 64, HID / 64), 256, 0, stream>>>(wk, wqkvT + (long)4096 * HID, HID, 1024);
  wtrans_kernel<<<dim3(1024 / 64, HID / 64), 256, 0, stream>>>(wv, wqkvT + (long)5120 * HID, HID, 1024);
  wtrans_kernel<<<dim3(HID / 64, HID / 64), 256, 0, stream>>>(wo, woT, HID, HID);
  gemm256<bf16><<<dim3(QKVN / 128, MROWS / 256), 512, R3_SMEM, stream>>>(h_bf, wqkvT, qkv, MROWS, QKVN, HID);
  ropek_kernel<<<(MROWS * 8 * 8) / 256, 256, 0, stream>>>(qkv, positions);
  dim3 t32(32, 8);
  vtrans_kernel<<<dim3(SEQ / 32, HD / 32, BATCH * NKVH), t32, 0, stream>>>(qkv, vtbuf);
  attn_kernel<<<dim3(8, NH, BATCH), 512, ATTN_SMEM, stream>>>(qkv, vtbuf, positions, attn);
  gemm8p<float><<<dim3(HID / 256, MROWS / 256), 512, G8P_SMEM, stream>>>(attn, woT, out, MROWS, HID, HID);
}

// Round 17
// 512.761 us; speedup vs baseline: 1.0060x; 1.0060x over previous
//
#include <hip/hip_runtime.h>
#include <cstdint>

typedef __bf16 bf16;
typedef __attribute__((ext_vector_type(4))) __bf16 bf16x4;
typedef __attribute__((ext_vector_type(8))) __bf16 bf16x8;
typedef __attribute__((ext_vector_type(4))) float f32x4;

#define DEVI __device__ __forceinline__

#define BATCH 2
#define SEQ 2048
#define HID 4096
#define NH 32
#define NKVH 8
#define HD 128
#define QKVN 6144
#define MROWS 4096
#define ATT_SCALE 0.08838834764831845f
#define QSCALE (0.08838834764831845f * 1.4426950408889634f)
#define ROPE_C (-0.2076205059304601f)   // -log2(10000)/64

DEVI void gload_lds16(const bf16* g, bf16* l) {
  __builtin_amdgcn_global_load_lds(
      (__attribute__((address_space(1))) void*)(g),
      (__attribute__((address_space(3))) void*)(l), 16, 0, 0);
}

// ---------------- elementwise f32 -> bf16 ----------------
__global__ void h2b_kernel(const float* __restrict__ in, bf16* __restrict__ out) {
  long i = ((long)blockIdx.x * 256 + threadIdx.x) * 4;
  float4 v = *(const float4*)(in + i);
  bf16x4 o;
  o[0] = (bf16)v.x; o[1] = (bf16)v.y; o[2] = (bf16)v.z; o[3] = (bf16)v.w;
  *(bf16x4*)(out + i) = o;
}

// ---------------- transpose-convert weight v1 (proven R11): (K,N) f32 -> (N,K) bf16 ----
__global__ void wtrans_kernel(const float* __restrict__ in, bf16* __restrict__ out,
                              int K, int N) {
  __shared__ float t[64][65];
  int n0 = blockIdx.x * 64, k0 = blockIdx.y * 64;
  int tid = threadIdx.x;
  int tx = tid & 15, ty = tid >> 4;   // 16 x 16
#pragma unroll
  for (int rr = 0; rr < 4; ++rr) {
    int k = ty * 4 + rr;
    float4 v = *(const float4*)(in + (long)(k0 + k) * N + n0 + tx * 4);
    t[k][tx * 4 + 0] = v.x; t[k][tx * 4 + 1] = v.y;
    t[k][tx * 4 + 2] = v.z; t[k][tx * 4 + 3] = v.w;
  }
  __syncthreads();
  int kc = tid & 7, nn = tid >> 3;    // 8 k-chunks x 32 n-rows
#pragma unroll
  for (int pp = 0; pp < 2; ++pp) {
    int n = nn + pp * 32;
    bf16x8 o;
#pragma unroll
    for (int j = 0; j < 8; ++j) o[j] = (bf16)t[kc * 8 + j][n];
    *(bf16x8*)(out + (long)(n0 + n) * K + k0 + kc * 8) = o;
  }
}

// ---------------- RoPE in-place, K columns ONLY (Q fused into attn) ----------------
__global__ void ropek_kernel(bf16* __restrict__ qkv, const int* __restrict__ pos) {
  long t = (long)blockIdx.x * 256 + threadIdx.x;   // MROWS*8*8 threads
  int d8 = (int)(t & 7) * 8;
  long u = t >> 3;
  int hh = (int)(u % 8);
  int row = (int)(u / 8);
  float p = (float)pos[row];
  bf16* base = qkv + (long)row * QKVN + 4096 + hh * HD + d8;
  bf16x8 x1v = *(const bf16x8*)(base);
  bf16x8 x2v = *(const bf16x8*)(base + 64);
  bf16x8 o1, o2;
#pragma unroll
  for (int j = 0; j < 8; ++j) {
    float ang = p * exp2f((float)(d8 + j) * ROPE_C);
    float sn, cs;
    __sincosf(ang, &sn, &cs);
    float x1 = (float)x1v[j], x2 = (float)x2v[j];
    o1[j] = (bf16)(x1 * cs - x2 * sn);
    o2[j] = (bf16)(x2 * cs + x1 * sn);
  }
  *(bf16x8*)(base) = o1;
  *(bf16x8*)(base + 64) = o2;
}

// ---------------- transpose V: qkv v-cols -> vt (b,kvh,D,S) ----------------
__global__ void vtrans_kernel(const bf16* __restrict__ qkv, bf16* __restrict__ vt) {
  __shared__ bf16 t[32][33];
  int s0 = blockIdx.x * 32, d0 = blockIdx.y * 32, bk = blockIdx.z;
  int b = bk >> 3, kvh = bk & 7;
  int tx = threadIdx.x, ty = threadIdx.y; // (32,8)
#pragma unroll
  for (int r = 0; r < 4; ++r) {
    int s = ty + r * 8;
    t[s][tx] = qkv[(long)(b * SEQ + s0 + s) * QKVN + 5120 + kvh * HD + d0 + tx];
  }
  __syncthreads();
#pragma unroll
  for (int r = 0; r < 4; ++r) {
    int d = ty + r * 8;
    vt[((long)bk * HD + d0 + d) * SEQ + s0 + tx] = t[tx][d];
  }
}

// ---------------- ring-3 GEMM (proven, GEMM1): C = A x BT^T ----------------
template <typename OutT>
__global__ __launch_bounds__(512, 2)
void gemm256(const bf16* __restrict__ A, const bf16* __restrict__ BT,
             OutT* __restrict__ C, int M, int N, int K) {
  extern __shared__ __align__(16) bf16 lds[];
  const int tid = threadIdx.x;
  const int lane = tid & 63, wave = tid >> 6;
  const int wm = wave >> 1, wn = wave & 1;
  const int l16 = lane & 15, lhi = lane >> 4;
  const int nwg = gridDim.x * gridDim.y;
  const int bid = blockIdx.y * gridDim.x + blockIdx.x;
  const int cpx = nwg >> 3;
  const int swz = (bid & 7) * cpx + (bid >> 3);
  const int bx = swz % gridDim.x, by = swz / gridDim.x;
  const long bm0 = (long)by * 256, bn0 = (long)bx * 128;

  const int srow8 = lane >> 3;
  const int scol = (lane & 7) ^ srow8;

  const int NT = K >> 6;
  f32x4 acc[4][4] = {};

  auto stage = [&](int slot, int t) {
    const long k0 = (long)t << 6;
    bf16* dst = lds + slot * 24576;
#pragma unroll
    for (int i = 0; i < 4; ++i) {
      int r = (wave * 4 + i) * 8 + srow8;
      gload_lds16(A + (bm0 + r) * K + k0 + scol * 8,
                  dst + (wave * 4 + i) * 512 + lane * 8);
    }
#pragma unroll
    for (int i = 0; i < 2; ++i) {
      int r = (wave * 2 + i) * 8 + srow8;
      gload_lds16(BT + (bn0 + r) * K + k0 + scol * 8,
                  dst + 16384 + (wave * 2 + i) * 512 + lane * 8);
    }
  };

  stage(0, 0);
  stage(1, 1);

  for (int t = 0; t < NT; ++t) {
    asm volatile("s_waitcnt vmcnt(6)" ::: "memory");
    __builtin_amdgcn_s_barrier();
    __builtin_amdgcn_sched_barrier(0);
    const int nxt = (t + 2 < NT) ? t + 2 : NT - 1;
    stage((t + 2) % 3, nxt);
    const bf16* As = lds + (t % 3) * 24576;
    const bf16* Bs = As + 16384;
#pragma unroll
    for (int kk = 0; kk < 2; ++kk) {
      bf16x8 af[4], bw[4];
#pragma unroll
      for (int i = 0; i < 4; ++i) {
        int ar = wm * 64 + i * 16 + l16;
        af[i] = *(const bf16x8*)(As + ar * 64 + (((kk * 4 + lhi) ^ (ar & 7))) * 8);
        int br = wn * 64 + i * 16 + l16;
        bw[i] = *(const bf16x8*)(Bs + br * 64 + (((kk * 4 + lhi) ^ (br & 7))) * 8);
      }
      __builtin_amdgcn_s_setprio(1);
#pragma unroll
      for (int i = 0; i < 4; ++i)
#pragma unroll
        for (int j = 0; j < 4; ++j)
          acc[i][j] = __builtin_amdgcn_mfma_f32_16x16x32_bf16(af[i], bw[j], acc[i][j], 0, 0, 0);
      __builtin_amdgcn_s_setprio(0);
    }
  }
  asm volatile("s_waitcnt vmcnt(0)" ::: "memory");
#pragma unroll
  for (int i = 0; i < 4; ++i)
#pragma unroll
    for (int r = 0; r < 4; ++r) {
      long grow = bm0 + wm * 64 + i * 16 + lhi * 4 + r;
#pragma unroll
      for (int j = 0; j < 4; ++j) {
        long gcol = bn0 + wn * 64 + j * 16 + l16;
        C[grow * N + gcol] = (OutT)acc[i][j][r];
      }
    }
}

// ---------------- 8-phase GEMM v3 (GEMM2): balanced reads 12/12/0/0 ----------------
// 256x256 tile, BK=64, 8 waves (2M x 4N). All current-tile LDS data is landed at
// tile entry (end-of-tile vmcnt(6)), so ALL ds_reads go in ph0 (a0+b0) and ph1
// (a1+b1); phases 2/3 are pure-register MFMA overlapping the t+2 stage issues.
// Stages: ph1 A-hi(t+1) [opp parity], ph2 A-lo(t+2)+B-lo(t+2), ph3 B-hi(t+2)
// (all four halves' reads complete by ph1-end barrier -> WAR-safe).
// FIFO at end-of-tile vmcnt(6): 14 outstanding, drains 8 oldest = all t+1 halves.
template <typename OutT>
__global__ __launch_bounds__(512, 2)
void gemm8p(const bf16* __restrict__ A, const bf16* __restrict__ BT,
            OutT* __restrict__ C, int M, int N, int K) {
  extern __shared__ __align__(16) bf16 lds[];
  const int tid = threadIdx.x;
  const int lane = tid & 63, wave = tid >> 6;
  const int wm = wave >> 2, wn = wave & 3;   // 2M x 4N
  const int l16 = lane & 15, lhi = lane >> 4;
  const int nwg = gridDim.x * gridDim.y;
  const int bid = blockIdx.y * gridDim.x + blockIdx.x;
  const int cpx = nwg >> 3;
  const int swz = (bid & 7) * cpx + (bid >> 3);
  const int bx = swz % gridDim.x, by = swz / gridDim.x;
  const long bm0 = (long)by * 256, bn0 = (long)bx * 256;

  bf16* Alds = lds;              // [2 buf][2 half][128][64]
  bf16* Blds = lds + 32768;
  const int NT = K >> 6;

  f32x4 acc[8][4] = {};

  auto stageH = [&](const bf16* src, long row0, long k0, bf16* dst) {
#pragma unroll
    for (int j = 0; j < 2; ++j) {
      int r = j * 64 + (tid >> 3);
      int sc = (tid & 7) ^ (r & 7);
      gload_lds16(src + (row0 + r) * (long)K + k0 + sc * 8,
                  dst + j * 4096 + tid * 8);
    }
  };

  // prologue: tile0 all 4 halves + tile1 {A-lo, B-lo, B-hi} = 14 loads
  stageH(A, bm0, 0, Alds);
  stageH(A, bm0 + 128, 0, Alds + 8192);
  stageH(BT, bn0, 0, Blds);
  stageH(BT, bn0 + 128, 0, Blds + 8192);
  {
    long k1p = (NT > 1) ? 64 : 0;
    stageH(A, bm0, k1p, Alds + 16384);
    stageH(BT, bn0, k1p, Blds + 16384);
    stageH(BT, bn0 + 128, k1p, Blds + 24576);
  }
  asm volatile("s_waitcnt vmcnt(6)" ::: "memory");
  __builtin_amdgcn_s_barrier();

  const int arow0 = wm * 128 + l16;
  const int brow0 = wn * 64 + l16;

  for (int t = 0; t < NT; ++t) {
    const bf16* Ab = Alds + (t & 1) * 16384;
    const bf16* Bb = Blds + (t & 1) * 16384;
    bf16* Aopp = Alds + ((t + 1) & 1) * 16384;
    bf16* Asame = Alds + (t & 1) * 16384;   // (t+2) parity == t parity
    bf16* Bsame = Blds + (t & 1) * 16384;
    const long k1 = (long)((t + 1 < NT) ? t + 1 : NT - 1) << 6;
    const long k2 = (long)((t + 2 < NT) ? t + 2 : NT - 1) << 6;

    bf16x8 a0[4][2], a1[4][2], b0[2][2], b1[2][2];
    // ---- phase 0: reads a0 (8) + b0 (4); MFMA q(mh0,np0)
#pragma unroll
    for (int i = 0; i < 4; ++i) {
      int mr = arow0 + i * 16;
#pragma unroll
      for (int kk = 0; kk < 2; ++kk)
        a0[i][kk] = *(const bf16x8*)(Ab + mr * 64 + (((kk * 4 + lhi) ^ (mr & 7))) * 8);
    }
#pragma unroll
    for (int n = 0; n < 2; ++n) {
      int br = brow0 + n * 16;
#pragma unroll
      for (int kk = 0; kk < 2; ++kk)
        b0[n][kk] = *(const bf16x8*)(Bb + br * 64 + (((kk * 4 + lhi) ^ (br & 7))) * 8);
    }
    __builtin_amdgcn_s_barrier();
    asm volatile("s_waitcnt lgkmcnt(0)" ::: "memory");
    __builtin_amdgcn_sched_barrier(0);
    __builtin_amdgcn_s_setprio(1);
#pragma unroll
    for (int i = 0; i < 4; ++i)
#pragma unroll
      for (int n = 0; n < 2; ++n)
#pragma unroll
        for (int kk = 0; kk < 2; ++kk)
          acc[i][n] = __builtin_amdgcn_mfma_f32_16x16x32_bf16(a0[i][kk], b0[n][kk], acc[i][n], 0, 0, 0);
    __builtin_amdgcn_s_setprio(0);
    __builtin_amdgcn_s_barrier();
    // ---- phase 1: reads a1 (8) + b1 (4); stage A-hi(t+1); MFMA q(mh1,np0)
#pragma unroll
    for (int i = 0; i < 4; ++i) {
      int mr = arow0 + 64 + i * 16;
#pragma unroll
      for (int kk = 0; kk < 2; ++kk)
        a1[i][kk] = *(const bf16x8*)(Ab + mr * 64 + (((kk * 4 + lhi) ^ (mr & 7))) * 8);
    }
#pragma unroll
    for (int n = 0; n < 2; ++n) {
      int br = brow0 + (n + 2) * 16;
#pragma unroll
      for (int kk = 0; kk < 2; ++kk)
        b1[n][kk] = *(const bf16x8*)(Bb + br * 64 + (((kk * 4 + lhi) ^ (br & 7))) * 8);
    }
    stageH(A, bm0 + 128, k1, Aopp + 8192);
    __builtin_amdgcn_s_barrier();
    asm volatile("s_waitcnt lgkmcnt(0)" ::: "memory");
    __builtin_amdgcn_sched_barrier(0);
    __builtin_amdgcn_s_setprio(1);
#pragma unroll
    for (int i = 0; i < 4; ++i)
#pragma unroll
      for (int n = 0; n < 2; ++n)
#pragma unroll
        for (int kk = 0; kk < 2; ++kk)
          acc[4 + i][n] = __builtin_amdgcn_mfma_f32_16x16x32_bf16(a1[i][kk], b0[n][kk], acc[4 + i][n], 0, 0, 0);
    __builtin_amdgcn_s_setprio(0);
    __builtin_amdgcn_s_barrier();
    // ---- phase 2: pure-reg MFMA q(mh1,np1); stage A-lo(t+2) + B-lo(t+2)
    stageH(A, bm0, k2, Asame);
    stageH(BT, bn0, k2, Bsame);
    __builtin_amdgcn_s_barrier();
    __builtin_amdgcn_s_setprio(1);
#pragma unroll
    for (int i = 0; i < 4; ++i)
#pragma unroll
      for (int n = 0; n < 2; ++n)
#pragma unroll
        for (int kk = 0; kk < 2; ++kk)
          acc[4 + i][n + 2] = __builtin_amdgcn_mfma_f32_16x16x32_bf16(a1[i][kk], b1[n][kk], acc[4 + i][n + 2], 0, 0, 0);
    __builtin_amdgcn_s_setprio(0);
    __builtin_amdgcn_s_barrier();
    // ---- phase 3: pure-reg MFMA q(mh0,np1); stage B-hi(t+2); vmcnt(6)
    stageH(BT, bn0 + 128, k2, Bsame + 8192);
    __builtin_amdgcn_s_barrier();
    __builtin_amdgcn_s_setprio(1);
#pragma unroll
    for (int i = 0; i < 4; ++i)
#pragma unroll
      for (int n = 0; n < 2; ++n)
#pragma unroll
        for (int kk = 0; kk < 2; ++kk)
          acc[i][n + 2] = __builtin_amdgcn_mfma_f32_16x16x32_bf16(a0[i][kk], b1[n][kk], acc[i][n + 2], 0, 0, 0);
    __builtin_amdgcn_s_setprio(0);
    asm volatile("s_waitcnt vmcnt(6)" ::: "memory");  // tile t+1 fully landed
    __builtin_amdgcn_s_barrier();
  }
  asm volatile("s_waitcnt vmcnt(0)" ::: "memory");
#pragma unroll
  for (int mi = 0; mi < 8; ++mi)
#pragma unroll
    for (int r = 0; r < 4; ++r) {
      long grow = bm0 + wm * 128 + mi * 16 + lhi * 4 + r;
#pragma unroll
      for (int n = 0; n < 4; ++n) {
        long gcol = bn0 + wn * 64 + n * 16 + l16;
        C[grow * N + gcol] = (OutT)acc[mi][n][r];
      }
    }
}

// ---------------- flash attention: balanced pairs + counted-vmcnt (proven) ----------------
__global__ __launch_bounds__(512, 4)
void attn_kernel(const bf16* __restrict__ qkv, const bf16* __restrict__ vt,
                 const int* __restrict__ pos, bf16* __restrict__ out) {
  extern __shared__ __align__(16) bf16 smem[];
  const int pi = blockIdx.x, h = blockIdx.y, b = blockIdx.z;
  const int kvh = h >> 2;
  const int tid = threadIdx.x, lane = tid & 63, wave = tid >> 6;
  const int l16 = lane & 15, lhi = lane >> 4;
  const int kloc = lhi * 4;
  bf16* Pw = smem + 32768 + wave * 1024;

  const bf16* kpan = qkv + (long)(b * SEQ) * QKVN + 4096 + kvh * HD;
  const bf16* vpan = vt + (long)(b * NKVH + kvh) * HD * SEQ;

  auto stageKV = [&](int buf, int step) {   // exactly 4 gload_lds per lane
    const int kv0 = step * 64;
    bf16* kd = smem + buf * 8192;
    bf16* vd = smem + 16384 + buf * 8192;
#pragma unroll
    for (int i = 0; i < 2; ++i) {
      int kr = wave * 8 + i * 4 + lhi;
      gload_lds16(kpan + (long)(kv0 + kr) * QKVN + (l16 ^ (kr & 7)) * 8,
                  kd + (wave * 8 + i * 4) * 128);
      int vr = wave * 16 + i * 8 + (lane >> 3);
      gload_lds16(vpan + (long)vr * SEQ + kv0 + ((lane & 7) ^ (vr & 7)) * 8,
                  vd + (wave * 16 + i * 8) * 64);
    }
  };

  auto process_chunk = [&](int q0, int nsteps) {
    const int qrow = q0 + wave * 16 + l16;
    float p = (float)pos[b * SEQ + qrow];
    const bf16* qb = qkv + (long)(b * SEQ + qrow) * QKVN + h * HD + lhi * 8;
    bf16x8 raw[4];
#pragma unroll
    for (int di = 0; di < 4; ++di) raw[di] = *(const bf16x8*)(qb + di * 32);
    bf16x8 qf[4];
#pragma unroll
    for (int pr = 0; pr < 2; ++pr)
#pragma unroll
      for (int j = 0; j < 8; ++j) {
        int d = lhi * 8 + pr * 32 + j;
        float ang = p * exp2f((float)d * ROPE_C);
        float sn, cs;
        __sincosf(ang, &sn, &cs);
        float x1 = (float)raw[pr][j], x2 = (float)raw[pr + 2][j];
        qf[pr][j] = (bf16)((x1 * cs - x2 * sn) * QSCALE);
        qf[pr + 2][j] = (bf16)((x2 * cs + x1 * sn) * QSCALE);
      }

    f32x4 oacc[8] = {};
    float m_run = -1e30f, l_run = 0.f;
    const int qg = qrow;
    const int qwmin = q0 + wave * 16;

    stageKV(0, 0);
    asm volatile("s_waitcnt vmcnt(0)" ::: "memory");
    __builtin_amdgcn_s_barrier();

    for (int step = 0; step < nsteps; ++step) {
      const int kv0 = step * 64;
      const int cur = step & 1;
      if (step + 1 < nsteps) {
        stageKV(cur ^ 1, step + 1);
        asm volatile("s_waitcnt vmcnt(4)" ::: "memory");
      } else {
        asm volatile("s_waitcnt vmcnt(0)" ::: "memory");
      }
      const bf16* Kc = smem + cur * 8192;
      const bf16* Vc = smem + 16384 + cur * 8192;

      f32x4 s[4];
      __builtin_amdgcn_s_setprio(1);
#pragma unroll
      for (int c = 0; c < 4; ++c) {
        s[c] = (f32x4){0.f, 0.f, 0.f, 0.f};
        int kr = c * 16 + l16;
#pragma unroll
        for (int di = 0; di < 4; ++di) {
          bf16x8 kf = *(const bf16x8*)(Kc + kr * 128 + (((di * 4 + lhi) ^ (kr & 7))) * 8);
          s[c] = __builtin_amdgcn_mfma_f32_16x16x32_bf16(kf, qf[di], s[c], 0, 0, 0);
        }
      }
      __builtin_amdgcn_s_setprio(0);
      if (kv0 + 63 > qwmin) {
#pragma unroll
        for (int c = 0; c < 4; ++c)
#pragma unroll
          for (int r = 0; r < 4; ++r) {
            int kcol = kv0 + c * 16 + kloc + r;
            if (kcol > qg) s[c][r] = -1e30f;
          }
      }
      float mloc = s[0][0];
#pragma unroll
      for (int c = 0; c < 4; ++c)
#pragma unroll
        for (int r = 0; r < 4; ++r) mloc = fmaxf(mloc, s[c][r]);
      mloc = fmaxf(mloc, __shfl_xor(mloc, 16, 64));
      mloc = fmaxf(mloc, __shfl_xor(mloc, 32, 64));
      bool skip = __all(mloc - m_run <= 8.0f);
      float alpha = 1.f;
      if (!skip) {
        float mn = fmaxf(m_run, mloc);
        alpha = exp2f(m_run - mn);
        m_run = mn;
      }
      float sm = 0.f;
      bf16x4 pb[4];
#pragma unroll
      for (int c = 0; c < 4; ++c)
#pragma unroll
        for (int r = 0; r < 4; ++r) {
          float pv = exp2f(s[c][r] - m_run);
          sm += pv;
          pb[c][r] = (bf16)pv;
        }
      sm += __shfl_xor(sm, 16, 64);
      sm += __shfl_xor(sm, 32, 64);
      l_run = l_run * alpha + sm;
#pragma unroll
      for (int c = 0; c < 4; ++c) {
        int sl = (c * 2 + (lhi >> 1)) ^ (l16 & 7);
        *(bf16x4*)(Pw + l16 * 64 + sl * 8 + (lhi & 1) * 4) = pb[c];
      }
      if (!skip) {
        float a_o[4];
#pragma unroll
        for (int r = 0; r < 4; ++r) a_o[r] = __shfl(alpha, kloc + r, 64);
#pragma unroll
        for (int dj = 0; dj < 8; ++dj)
#pragma unroll
          for (int r = 0; r < 4; ++r) oacc[dj][r] *= a_o[r];
      }
      __builtin_amdgcn_s_setprio(1);
#pragma unroll
      for (int kh = 0; kh < 2; ++kh) {
        bf16x8 pf = *(const bf16x8*)(Pw + l16 * 64 + (((kh * 4 + lhi) ^ (l16 & 7))) * 8);
#pragma unroll
        for (int dj = 0; dj < 8; ++dj) {
          int vr = dj * 16 + l16;
          bf16x8 vf = *(const bf16x8*)(Vc + vr * 64 + (((kh * 4 + lhi) ^ (vr & 7))) * 8);
          oacc[dj] = __builtin_amdgcn_mfma_f32_16x16x32_bf16(pf, vf, oacc[dj], 0, 0, 0);
        }
      }
      __builtin_amdgcn_s_setprio(0);
      __builtin_amdgcn_s_barrier();
    }
    float linv[4];
#pragma unroll
    for (int r = 0; r < 4; ++r) linv[r] = 1.f / __shfl(l_run, kloc + r, 64);
#pragma unroll
    for (int r = 0; r < 4; ++r) {
      long orow = (long)(b * SEQ + q0 + wave * 16 + lhi * 4 + r);
#pragma unroll
      for (int dj = 0; dj < 8; ++dj)
        out[orow * (NH * HD) + h * HD + dj * 16 + l16] = (bf16)(oacc[dj][r] * linv[r]);
    }
  };

  process_chunk(pi * 128, 2 * pi + 2);
  process_chunk((15 - pi) * 128, 32 - 2 * pi);
}

extern "C" void kernel_launch(void* const* d_in, const int* in_sizes, int n_in,
                              void* d_out, int out_size, void* d_ws, size_t ws_size,
                              hipStream_t stream) {
  const int* positions = (const int*)d_in[0];
  const float* hidden = (const float*)d_in[1];
  const float* wq = (const float*)d_in[2];
  const float* wk = (const float*)d_in[3];
  const float* wv = (const float*)d_in[4];
  const float* wo = (const float*)d_in[5];
  float* out = (float*)d_out;
  char* ws = (char*)d_ws;

  const size_t SZ_H = (size_t)MROWS * HID * 2;
  const size_t SZ_WQKV = (size_t)QKVN * HID * 2;
  const size_t SZ_WO = (size_t)HID * HID * 2;
  bf16* h_bf = (bf16*)(ws);
  bf16* wqkvT = (bf16*)(ws + SZ_H);
  bf16* woT = (bf16*)(ws + SZ_H + SZ_WQKV);
  bf16* qkv = (bf16*)(ws + SZ_H + SZ_WQKV + SZ_WO);
  bf16* attn = h_bf;
  bf16* vtbuf = wqkvT;

  const int G8P_SMEM = 131072;
  const int R3_SMEM = 3 * 24576 * 2;
  const int ATTN_SMEM = 40960 * 2;
  auto* g1 = gemm256<bf16>;
  auto* g2 = gemm8p<float>;
  hipFuncSetAttribute(reinterpret_cast<const void*>(g1),
                      hipFuncAttributeMaxDynamicSharedMemorySize, R3_SMEM);
  hipFuncSetAttribute(reinterpret_cast<const void*>(g2),
                      hipFuncAttributeMaxDynamicSharedMemorySize, G8P_SMEM);
  hipFuncSetAttribute(reinterpret_cast<const void*>(attn_kernel),
                      hipFuncAttributeMaxDynamicSharedMemorySize, ATTN_SMEM);

  h2b_kernel<<<(MROWS * (long)HID) / (256 * 4), 256, 0, stream>>>(hidden, h_bf);
  wtrans_kernel<<<dim3(HID / 64, HID / 64), 256, 0, stream>>>(wq, wqkvT, HID, HID);
  wtrans_kernel<<<dim3(1024 / 64, HID / 64), 256, 0, stream>>>(wk, wqkvT + (long)4096 * HID, HID, 1024);
  wtrans_kernel<<<dim3(1024 / 64, HID / 64), 256, 0, stream>>>(wv, wqkvT + (long)5120 * HID, HID, 1024);
  wtrans_kernel<<<dim3(HID / 64, HID / 64), 256, 0, stream>>>(wo, woT, HID, HID);
  gemm256<bf16><<<dim3(QKVN / 128, MROWS / 256), 512, R3_SMEM, stream>>>(h_bf, wqkvT, qkv, MROWS, QKVN, HID);
  ropek_kernel<<<(MROWS * 8 * 8) / 256, 256, 0, stream>>>(qkv, positions);
  dim3 t32(32, 8);
  vtrans_kernel<<<dim3(SEQ / 32, HD / 32, BATCH * NKVH), t32, 0, stream>>>(qkv, vtbuf);
  attn_kernel<<<dim3(8, NH, BATCH), 512, ATTN_SMEM, stream>>>(qkv, vtbuf, positions, attn);
  gemm8p<float><<<dim3(HID / 256, MROWS / 256), 512, G8P_SMEM, stream>>>(attn, woT, out, MROWS, HID, HID);
}

// Round 18
// 509.655 us; speedup vs baseline: 1.0121x; 1.0061x over previous
//
#include <hip/hip_runtime.h>
#include <cstdint>

typedef __bf16 bf16;
typedef __attribute__((ext_vector_type(4))) __bf16 bf16x4;
typedef __attribute__((ext_vector_type(8))) __bf16 bf16x8;
typedef __attribute__((ext_vector_type(4))) float f32x4;

#define DEVI __device__ __forceinline__

#define BATCH 2
#define SEQ 2048
#define HID 4096
#define NH 32
#define NKVH 8
#define HD 128
#define QKVN 6144
#define MROWS 4096
#define ATT_SCALE 0.08838834764831845f
#define QSCALE (0.08838834764831845f * 1.4426950408889634f)
#define ROPE_C (-0.2076205059304601f)   // -log2(10000)/64

DEVI void gload_lds16(const bf16* g, bf16* l) {
  __builtin_amdgcn_global_load_lds(
      (__attribute__((address_space(1))) void*)(g),
      (__attribute__((address_space(3))) void*)(l), 16, 0, 0);
}

// ---------------- elementwise f32 -> bf16 ----------------
__global__ void h2b_kernel(const float* __restrict__ in, bf16* __restrict__ out) {
  long i = ((long)blockIdx.x * 256 + threadIdx.x) * 4;
  float4 v = *(const float4*)(in + i);
  bf16x4 o;
  o[0] = (bf16)v.x; o[1] = (bf16)v.y; o[2] = (bf16)v.z; o[3] = (bf16)v.w;
  *(bf16x4*)(out + i) = o;
}

// ---------------- transpose-convert weight v1 (proven R11): (K,N) f32 -> (N,K) bf16 ----
__global__ void wtrans_kernel(const float* __restrict__ in, bf16* __restrict__ out,
                              int K, int N) {
  __shared__ float t[64][65];
  int n0 = blockIdx.x * 64, k0 = blockIdx.y * 64;
  int tid = threadIdx.x;
  int tx = tid & 15, ty = tid >> 4;   // 16 x 16
#pragma unroll
  for (int rr = 0; rr < 4; ++rr) {
    int k = ty * 4 + rr;
    float4 v = *(const float4*)(in + (long)(k0 + k) * N + n0 + tx * 4);
    t[k][tx * 4 + 0] = v.x; t[k][tx * 4 + 1] = v.y;
    t[k][tx * 4 + 2] = v.z; t[k][tx * 4 + 3] = v.w;
  }
  __syncthreads();
  int kc = tid & 7, nn = tid >> 3;    // 8 k-chunks x 32 n-rows
#pragma unroll
  for (int pp = 0; pp < 2; ++pp) {
    int n = nn + pp * 32;
    bf16x8 o;
#pragma unroll
    for (int j = 0; j < 8; ++j) o[j] = (bf16)t[kc * 8 + j][n];
    *(bf16x8*)(out + (long)(n0 + n) * K + k0 + kc * 8) = o;
  }
}

// ---------------- RoPE in-place, K columns ONLY (Q fused into attn) ----------------
__global__ void ropek_kernel(bf16* __restrict__ qkv, const int* __restrict__ pos) {
  long t = (long)blockIdx.x * 256 + threadIdx.x;   // MROWS*8*8 threads
  int d8 = (int)(t & 7) * 8;
  long u = t >> 3;
  int hh = (int)(u % 8);
  int row = (int)(u / 8);
  float p = (float)pos[row];
  bf16* base = qkv + (long)row * QKVN + 4096 + hh * HD + d8;
  bf16x8 x1v = *(const bf16x8*)(base);
  bf16x8 x2v = *(const bf16x8*)(base + 64);
  bf16x8 o1, o2;
#pragma unroll
  for (int j = 0; j < 8; ++j) {
    float ang = p * exp2f((float)(d8 + j) * ROPE_C);
    float sn, cs;
    __sincosf(ang, &sn, &cs);
    float x1 = (float)x1v[j], x2 = (float)x2v[j];
    o1[j] = (bf16)(x1 * cs - x2 * sn);
    o2[j] = (bf16)(x2 * cs + x1 * sn);
  }
  *(bf16x8*)(base) = o1;
  *(bf16x8*)(base + 64) = o2;
}

// ---------------- transpose V: qkv v-cols -> vt (b,kvh,D,S) ----------------
__global__ void vtrans_kernel(const bf16* __restrict__ qkv, bf16* __restrict__ vt) {
  __shared__ bf16 t[32][33];
  int s0 = blockIdx.x * 32, d0 = blockIdx.y * 32, bk = blockIdx.z;
  int b = bk >> 3, kvh = bk & 7;
  int tx = threadIdx.x, ty = threadIdx.y; // (32,8)
#pragma unroll
  for (int r = 0; r < 4; ++r) {
    int s = ty + r * 8;
    t[s][tx] = qkv[(long)(b * SEQ + s0 + s) * QKVN + 5120 + kvh * HD + d0 + tx];
  }
  __syncthreads();
#pragma unroll
  for (int r = 0; r < 4; ++r) {
    int d = ty + r * 8;
    vt[((long)bk * HD + d0 + d) * SEQ + s0 + tx] = t[tx][d];
  }
}

// ---------------- ring-3 GEMM (proven, GEMM1): C = A x BT^T ----------------
template <typename OutT>
__global__ __launch_bounds__(512, 2)
void gemm256(const bf16* __restrict__ A, const bf16* __restrict__ BT,
             OutT* __restrict__ C, int M, int N, int K) {
  extern __shared__ __align__(16) bf16 lds[];
  const int tid = threadIdx.x;
  const int lane = tid & 63, wave = tid >> 6;
  const int wm = wave >> 1, wn = wave & 1;
  const int l16 = lane & 15, lhi = lane >> 4;
  const int nwg = gridDim.x * gridDim.y;
  const int bid = blockIdx.y * gridDim.x + blockIdx.x;
  const int cpx = nwg >> 3;
  const int swz = (bid & 7) * cpx + (bid >> 3);
  const int bx = swz % gridDim.x, by = swz / gridDim.x;
  const long bm0 = (long)by * 256, bn0 = (long)bx * 128;

  const int srow8 = lane >> 3;
  const int scol = (lane & 7) ^ srow8;

  const int NT = K >> 6;
  f32x4 acc[4][4] = {};

  auto stage = [&](int slot, int t) {
    const long k0 = (long)t << 6;
    bf16* dst = lds + slot * 24576;
#pragma unroll
    for (int i = 0; i < 4; ++i) {
      int r = (wave * 4 + i) * 8 + srow8;
      gload_lds16(A + (bm0 + r) * K + k0 + scol * 8,
                  dst + (wave * 4 + i) * 512 + lane * 8);
    }
#pragma unroll
    for (int i = 0; i < 2; ++i) {
      int r = (wave * 2 + i) * 8 + srow8;
      gload_lds16(BT + (bn0 + r) * K + k0 + scol * 8,
                  dst + 16384 + (wave * 2 + i) * 512 + lane * 8);
    }
  };

  stage(0, 0);
  stage(1, 1);

  for (int t = 0; t < NT; ++t) {
    asm volatile("s_waitcnt vmcnt(6)" ::: "memory");
    __builtin_amdgcn_s_barrier();
    __builtin_amdgcn_sched_barrier(0);
    const int nxt = (t + 2 < NT) ? t + 2 : NT - 1;
    stage((t + 2) % 3, nxt);
    const bf16* As = lds + (t % 3) * 24576;
    const bf16* Bs = As + 16384;
#pragma unroll
    for (int kk = 0; kk < 2; ++kk) {
      bf16x8 af[4], bw[4];
#pragma unroll
      for (int i = 0; i < 4; ++i) {
        int ar = wm * 64 + i * 16 + l16;
        af[i] = *(const bf16x8*)(As + ar * 64 + (((kk * 4 + lhi) ^ (ar & 7))) * 8);
        int br = wn * 64 + i * 16 + l16;
        bw[i] = *(const bf16x8*)(Bs + br * 64 + (((kk * 4 + lhi) ^ (br & 7))) * 8);
      }
      __builtin_amdgcn_s_setprio(1);
#pragma unroll
      for (int i = 0; i < 4; ++i)
#pragma unroll
        for (int j = 0; j < 4; ++j)
          acc[i][j] = __builtin_amdgcn_mfma_f32_16x16x32_bf16(af[i], bw[j], acc[i][j], 0, 0, 0);
      __builtin_amdgcn_s_setprio(0);
    }
  }
  asm volatile("s_waitcnt vmcnt(0)" ::: "memory");
#pragma unroll
  for (int i = 0; i < 4; ++i)
#pragma unroll
    for (int r = 0; r < 4; ++r) {
      long grow = bm0 + wm * 64 + i * 16 + lhi * 4 + r;
#pragma unroll
      for (int j = 0; j < 4; ++j) {
        long gcol = bn0 + wn * 64 + j * 16 + l16;
        C[grow * N + gcol] = (OutT)acc[i][j][r];
      }
    }
}

// ---------------- 8-phase GEMM v2 (GEMM2: 4096^2, grid 256 = exactly 1/CU) ----------------
template <typename OutT>
__global__ __launch_bounds__(512, 2)
void gemm8p(const bf16* __restrict__ A, const bf16* __restrict__ BT,
            OutT* __restrict__ C, int M, int N, int K) {
  extern __shared__ __align__(16) bf16 lds[];
  const int tid = threadIdx.x;
  const int lane = tid & 63, wave = tid >> 6;
  const int wm = wave >> 2, wn = wave & 3;   // 2M x 4N
  const int l16 = lane & 15, lhi = lane >> 4;
  const int nwg = gridDim.x * gridDim.y;
  const int bid = blockIdx.y * gridDim.x + blockIdx.x;
  const int cpx = nwg >> 3;
  const int swz = (bid & 7) * cpx + (bid >> 3);
  const int bx = swz % gridDim.x, by = swz / gridDim.x;
  const long bm0 = (long)by * 256, bn0 = (long)bx * 256;

  bf16* Alds = lds;              // [2 buf][2 half][128][64]
  bf16* Blds = lds + 32768;
  const int NT = K >> 6;

  f32x4 acc[8][4] = {};

  auto stageH = [&](const bf16* src, long row0, long k0, bf16* dst) {
#pragma unroll
    for (int j = 0; j < 2; ++j) {
      int r = j * 64 + (tid >> 3);
      int sc = (tid & 7) ^ (r & 7);
      gload_lds16(src + (row0 + r) * (long)K + k0 + sc * 8,
                  dst + j * 4096 + tid * 8);
    }
  };

  stageH(A, bm0, 0, Alds);
  stageH(A, bm0 + 128, 0, Alds + 8192);
  stageH(BT, bn0, 0, Blds);
  stageH(BT, bn0 + 128, 0, Blds + 8192);
  {
    long k1p = (NT > 1) ? 64 : 0;
    stageH(BT, bn0, k1p, Blds + 16384);
    stageH(BT, bn0 + 128, k1p, Blds + 24576);
    stageH(A, bm0, k1p, Alds + 16384);
  }
  asm volatile("s_waitcnt vmcnt(6)" ::: "memory");
  __builtin_amdgcn_s_barrier();

  const int arow0 = wm * 128 + l16;
  const int brow0 = wn * 64 + l16;

  for (int t = 0; t < NT; ++t) {
    const bf16* Ab = Alds + (t & 1) * 16384;
    const bf16* Bb = Blds + (t & 1) * 16384;
    bf16* Aopp = Alds + ((t + 1) & 1) * 16384;
    bf16* Asame = Alds + (t & 1) * 16384;
    bf16* Bsame = Blds + (t & 1) * 16384;
    const long k1 = (long)((t + 1 < NT) ? t + 1 : NT - 1) << 6;
    const long k2 = (long)((t + 2 < NT) ? t + 2 : NT - 1) << 6;

    bf16x8 a0[4][2], a1[4][2], b0[2][2], b1[2][2];
    // phase 0: reads a0+b0; MFMA q(mh0,np0)
#pragma unroll
    for (int i = 0; i < 4; ++i) {
      int mr = arow0 + i * 16;
#pragma unroll
      for (int kk = 0; kk < 2; ++kk)
        a0[i][kk] = *(const bf16x8*)(Ab + mr * 64 + (((kk * 4 + lhi) ^ (mr & 7))) * 8);
    }
#pragma unroll
    for (int n = 0; n < 2; ++n) {
      int br = brow0 + n * 16;
#pragma unroll
      for (int kk = 0; kk < 2; ++kk)
        b0[n][kk] = *(const bf16x8*)(Bb + br * 64 + (((kk * 4 + lhi) ^ (br & 7))) * 8);
    }
    __builtin_amdgcn_s_barrier();
    asm volatile("s_waitcnt lgkmcnt(0)" ::: "memory");
    __builtin_amdgcn_sched_barrier(0);
    __builtin_amdgcn_s_setprio(1);
#pragma unroll
    for (int i = 0; i < 4; ++i)
#pragma unroll
      for (int n = 0; n < 2; ++n)
#pragma unroll
        for (int kk = 0; kk < 2; ++kk)
          acc[i][n] = __builtin_amdgcn_mfma_f32_16x16x32_bf16(a0[i][kk], b0[n][kk], acc[i][n], 0, 0, 0);
    __builtin_amdgcn_s_setprio(0);
    __builtin_amdgcn_s_barrier();
    // phase 1: reads a1; stage A-hi(t+1); MFMA q(mh1,np0)
#pragma unroll
    for (int i = 0; i < 4; ++i) {
      int mr = arow0 + 64 + i * 16;
#pragma unroll
      for (int kk = 0; kk < 2; ++kk)
        a1[i][kk] = *(const bf16x8*)(Ab + mr * 64 + (((kk * 4 + lhi) ^ (mr & 7))) * 8);
    }
    stageH(A, bm0 + 128, k1, Aopp + 8192);
    __builtin_amdgcn_s_barrier();
    asm volatile("s_waitcnt lgkmcnt(0)" ::: "memory");
    __builtin_amdgcn_sched_barrier(0);
    __builtin_amdgcn_s_setprio(1);
#pragma unroll
    for (int i = 0; i < 4; ++i)
#pragma unroll
      for (int n = 0; n < 2; ++n)
#pragma unroll
        for (int kk = 0; kk < 2; ++kk)
          acc[4 + i][n] = __builtin_amdgcn_mfma_f32_16x16x32_bf16(a1[i][kk], b0[n][kk], acc[4 + i][n], 0, 0, 0);
    __builtin_amdgcn_s_setprio(0);
    __builtin_amdgcn_s_barrier();
    // phase 2: reads b1; stage A-lo(t+2); MFMA q(mh1,np1)
#pragma unroll
    for (int n = 0; n < 2; ++n) {
      int br = brow0 + (n + 2) * 16;
#pragma unroll
      for (int kk = 0; kk < 2; ++kk)
        b1[n][kk] = *(const bf16x8*)(Bb + br * 64 + (((kk * 4 + lhi) ^ (br & 7))) * 8);
    }
    stageH(A, bm0, k2, Asame);
    __builtin_amdgcn_s_barrier();
    asm volatile("s_waitcnt lgkmcnt(0)" ::: "memory");
    __builtin_amdgcn_sched_barrier(0);
    __builtin_amdgcn_s_setprio(1);
#pragma unroll
    for (int i = 0; i < 4; ++i)
#pragma unroll
      for (int n = 0; n < 2; ++n)
#pragma unroll
        for (int kk = 0; kk < 2; ++kk)
          acc[4 + i][n + 2] = __builtin_amdgcn_mfma_f32_16x16x32_bf16(a1[i][kk], b1[n][kk], acc[4 + i][n + 2], 0, 0, 0);
    __builtin_amdgcn_s_setprio(0);
    __builtin_amdgcn_s_barrier();
    // phase 3: stage B-lo+B-hi(t+2); MFMA q(mh0,np1); vmcnt(6)
    stageH(BT, bn0, k2, Bsame);
    stageH(BT, bn0 + 128, k2, Bsame + 8192);
    __builtin_amdgcn_s_barrier();
    __builtin_amdgcn_s_setprio(1);
#pragma unroll
    for (int i = 0; i < 4; ++i)
#pragma unroll
      for (int n = 0; n < 2; ++n)
#pragma unroll
        for (int kk = 0; kk < 2; ++kk)
          acc[i][n + 2] = __builtin_amdgcn_mfma_f32_16x16x32_bf16(a0[i][kk], b1[n][kk], acc[i][n + 2], 0, 0, 0);
    __builtin_amdgcn_s_setprio(0);
    asm volatile("s_waitcnt vmcnt(6)" ::: "memory");
    __builtin_amdgcn_s_barrier();
  }
  asm volatile("s_waitcnt vmcnt(0)" ::: "memory");
#pragma unroll
  for (int mi = 0; mi < 8; ++mi)
#pragma unroll
    for (int r = 0; r < 4; ++r) {
      long grow = bm0 + wm * 128 + mi * 16 + lhi * 4 + r;
#pragma unroll
      for (int n = 0; n < 4; ++n) {
        long gcol = bn0 + wn * 64 + n * 16 + l16;
        C[grow * N + gcol] = (OutT)acc[mi][n][r];
      }
    }
}

// ---------------- flash attention: balanced pairs + fused Q-RoPE + mask hoist (R11) -----
__global__ __launch_bounds__(512, 4)
void attn_kernel(const bf16* __restrict__ qkv, const bf16* __restrict__ vt,
                 const int* __restrict__ pos, bf16* __restrict__ out) {
  extern __shared__ __align__(16) bf16 smem[];
  const int pi = blockIdx.x, h = blockIdx.y, b = blockIdx.z;
  const int kvh = h >> 2;
  const int tid = threadIdx.x, lane = tid & 63, wave = tid >> 6;
  const int l16 = lane & 15, lhi = lane >> 4;
  const int kloc = lhi * 4;
  bf16* Pw = smem + 32768 + wave * 1024;

  const bf16* kpan = qkv + (long)(b * SEQ) * QKVN + 4096 + kvh * HD;
  const bf16* vpan = vt + (long)(b * NKVH + kvh) * HD * SEQ;

  auto stageKV = [&](int buf, int step) {
    const int kv0 = step * 64;
    bf16* kd = smem + buf * 8192;
    bf16* vd = smem + 16384 + buf * 8192;
#pragma unroll
    for (int i = 0; i < 2; ++i) {
      int kr = wave * 8 + i * 4 + lhi;
      gload_lds16(kpan + (long)(kv0 + kr) * QKVN + (l16 ^ (kr & 7)) * 8,
                  kd + (wave * 8 + i * 4) * 128);
      int vr = wave * 16 + i * 8 + (lane >> 3);
      gload_lds16(vpan + (long)vr * SEQ + kv0 + ((lane & 7) ^ (vr & 7)) * 8,
                  vd + (wave * 16 + i * 8) * 64);
    }
  };

  auto process_chunk = [&](int q0, int nsteps) {
    const int qrow = q0 + wave * 16 + l16;
    float p = (float)pos[b * SEQ + qrow];
    const bf16* qb = qkv + (long)(b * SEQ + qrow) * QKVN + h * HD + lhi * 8;
    bf16x8 raw[4];
#pragma unroll
    for (int di = 0; di < 4; ++di) raw[di] = *(const bf16x8*)(qb + di * 32);
    bf16x8 qf[4];
#pragma unroll
    for (int pr = 0; pr < 2; ++pr)
#pragma unroll
      for (int j = 0; j < 8; ++j) {
        int d = lhi * 8 + pr * 32 + j;
        float ang = p * exp2f((float)d * ROPE_C);
        float sn, cs;
        __sincosf(ang, &sn, &cs);
        float x1 = (float)raw[pr][j], x2 = (float)raw[pr + 2][j];
        qf[pr][j] = (bf16)((x1 * cs - x2 * sn) * QSCALE);
        qf[pr + 2][j] = (bf16)((x2 * cs + x1 * sn) * QSCALE);
      }

    f32x4 oacc[8] = {};
    float m_run = -1e30f, l_run = 0.f;
    const int qg = qrow;
    const int qwmin = q0 + wave * 16;

    stageKV(0, 0);
    __syncthreads();

    for (int step = 0; step < nsteps; ++step) {
      const int kv0 = step * 64;
      const int cur = step & 1;
      if (step + 1 < nsteps) stageKV(cur ^ 1, step + 1);
      const bf16* Kc = smem + cur * 8192;
      const bf16* Vc = smem + 16384 + cur * 8192;

      f32x4 s[4];
      __builtin_amdgcn_s_setprio(1);
#pragma unroll
      for (int c = 0; c < 4; ++c) {
        s[c] = (f32x4){0.f, 0.f, 0.f, 0.f};
        int kr = c * 16 + l16;
#pragma unroll
        for (int di = 0; di < 4; ++di) {
          bf16x8 kf = *(const bf16x8*)(Kc + kr * 128 + (((di * 4 + lhi) ^ (kr & 7))) * 8);
          s[c] = __builtin_amdgcn_mfma_f32_16x16x32_bf16(kf, qf[di], s[c], 0, 0, 0);
        }
      }
      __builtin_amdgcn_s_setprio(0);
      if (kv0 + 63 > qwmin) {
#pragma unroll
        for (int c = 0; c < 4; ++c)
#pragma unroll
          for (int r = 0; r < 4; ++r) {
            int kcol = kv0 + c * 16 + kloc + r;
            if (kcol > qg) s[c][r] = -1e30f;
          }
      }
      float mloc = s[0][0];
#pragma unroll
      for (int c = 0; c < 4; ++c)
#pragma unroll
        for (int r = 0; r < 4; ++r) mloc = fmaxf(mloc, s[c][r]);
      mloc = fmaxf(mloc, __shfl_xor(mloc, 16, 64));
      mloc = fmaxf(mloc, __shfl_xor(mloc, 32, 64));
      bool skip = __all(mloc - m_run <= 8.0f);
      float alpha = 1.f;
      if (!skip) {
        float mn = fmaxf(m_run, mloc);
        alpha = exp2f(m_run - mn);
        m_run = mn;
      }
      float sm = 0.f;
      bf16x4 pb[4];
#pragma unroll
      for (int c = 0; c < 4; ++c)
#pragma unroll
        for (int r = 0; r < 4; ++r) {
          float pv = exp2f(s[c][r] - m_run);
          sm += pv;
          pb[c][r] = (bf16)pv;
        }
      sm += __shfl_xor(sm, 16, 64);
      sm += __shfl_xor(sm, 32, 64);
      l_run = l_run * alpha + sm;
#pragma unroll
      for (int c = 0; c < 4; ++c) {
        int sl = (c * 2 + (lhi >> 1)) ^ (l16 & 7);
        *(bf16x4*)(Pw + l16 * 64 + sl * 8 + (lhi & 1) * 4) = pb[c];
      }
      if (!skip) {
        float a_o[4];
#pragma unroll
        for (int r = 0; r < 4; ++r) a_o[r] = __shfl(alpha, kloc + r, 64);
#pragma unroll
        for (int dj = 0; dj < 8; ++dj)
#pragma unroll
          for (int r = 0; r < 4; ++r) oacc[dj][r] *= a_o[r];
      }
      __builtin_amdgcn_s_setprio(1);
#pragma unroll
      for (int kh = 0; kh < 2; ++kh) {
        bf16x8 pf = *(const bf16x8*)(Pw + l16 * 64 + (((kh * 4 + lhi) ^ (l16 & 7))) * 8);
#pragma unroll
        for (int dj = 0; dj < 8; ++dj) {
          int vr = dj * 16 + l16;
          bf16x8 vf = *(const bf16x8*)(Vc + vr * 64 + (((kh * 4 + lhi) ^ (vr & 7))) * 8);
          oacc[dj] = __builtin_amdgcn_mfma_f32_16x16x32_bf16(pf, vf, oacc[dj], 0, 0, 0);
        }
      }
      __builtin_amdgcn_s_setprio(0);
      __syncthreads();
    }
    float linv[4];
#pragma unroll
    for (int r = 0; r < 4; ++r) linv[r] = 1.f / __shfl(l_run, kloc + r, 64);
#pragma unroll
    for (int r = 0; r < 4; ++r) {
      long orow = (long)(b * SEQ + q0 + wave * 16 + lhi * 4 + r);
#pragma unroll
      for (int dj = 0; dj < 8; ++dj)
        out[orow * (NH * HD) + h * HD + dj * 16 + l16] = (bf16)(oacc[dj][r] * linv[r]);
    }
  };

  process_chunk(pi * 128, 2 * pi + 2);
  process_chunk((15 - pi) * 128, 32 - 2 * pi);
}

extern "C" void kernel_launch(void* const* d_in, const int* in_sizes, int n_in,
                              void* d_out, int out_size, void* d_ws, size_t ws_size,
                              hipStream_t stream) {
  const int* positions = (const int*)d_in[0];
  const float* hidden = (const float*)d_in[1];
  const float* wq = (const float*)d_in[2];
  const float* wk = (const float*)d_in[3];
  const float* wv = (const float*)d_in[4];
  const float* wo = (const float*)d_in[5];
  float* out = (float*)d_out;
  char* ws = (char*)d_ws;

  const size_t SZ_H = (size_t)MROWS * HID * 2;
  const size_t SZ_WQKV = (size_t)QKVN * HID * 2;
  const size_t SZ_WO = (size_t)HID * HID * 2;
  bf16* h_bf = (bf16*)(ws);
  bf16* wqkvT = (bf16*)(ws + SZ_H);
  bf16* woT = (bf16*)(ws + SZ_H + SZ_WQKV);
  bf16* qkv = (bf16*)(ws + SZ_H + SZ_WQKV + SZ_WO);
  bf16* attn = h_bf;
  bf16* vtbuf = wqkvT;

  const int G8P_SMEM = 131072;
  const int R3_SMEM = 3 * 24576 * 2;
  const int ATTN_SMEM = 40960 * 2;
  auto* g1 = gemm256<bf16>;
  auto* g2 = gemm8p<float>;
  hipFuncSetAttribute(reinterpret_cast<const void*>(g1),
                      hipFuncAttributeMaxDynamicSharedMemorySize, R3_SMEM);
  hipFuncSetAttribute(reinterpret_cast<const void*>(g2),
                      hipFuncAttributeMaxDynamicSharedMemorySize, G8P_SMEM);
  hipFuncSetAttribute(reinterpret_cast<const void*>(attn_kernel),
                      hipFuncAttributeMaxDynamicSharedMemorySize, ATTN_SMEM);

  h2b_kernel<<<(MROWS * (long)HID) / (256 * 4), 256, 0, stream>>>(hidden, h_bf);
  wtrans_kernel<<<dim3(HID / 64, HID / 64), 256, 0, stream>>>(wq, wqkvT, HID, HID);
  wtrans_kernel<<<dim3(1024 / 64, HID / 64), 256, 0, stream>>>(wk, wqkvT + (long)4096 * HID, HID, 1024);
  wtrans_kernel<<<dim3(1024 / 64, HID / 64), 256, 0, stream>>>(wv, wqkvT + (long)5120 * HID, HID, 1024);
  wtrans_kernel<<<dim3(HID / 64, HID / 64), 256, 0, stream>>>(wo, woT, HID, HID);
  gemm256<bf16><<<dim3(QKVN / 128, MROWS / 256), 512, R3_SMEM, stream>>>(h_bf, wqkvT, qkv, MROWS, QKVN, HID);
  ropek_kernel<<<(MROWS * 8 * 8) / 256, 256, 0, stream>>>(qkv, positions);
  dim3 t32(32, 8);
  vtrans_kernel<<<dim3(SEQ / 32, HD / 32, BATCH * NKVH), t32, 0, stream>>>(qkv, vtbuf);
  attn_kernel<<<dim3(8, NH, BATCH), 512, ATTN_SMEM, stream>>>(qkv, vtbuf, positions, attn);
  gemm8p<float><<<dim3(HID / 256, MROWS / 256), 512, G8P_SMEM, stream>>>(attn, woT, out, MROWS, HID, HID);
}

// Round 19
// 503.395 us; speedup vs baseline: 1.0247x; 1.0124x over previous
//
#include <hip/hip_runtime.h>
#include <cstdint>

typedef __bf16 bf16;
typedef __attribute__((ext_vector_type(4))) __bf16 bf16x4;
typedef __attribute__((ext_vector_type(8))) __bf16 bf16x8;
typedef __attribute__((ext_vector_type(4))) float f32x4;

#define DEVI __device__ __forceinline__

#define BATCH 2
#define SEQ 2048
#define HID 4096
#define NH 32
#define NKVH 8
#define HD 128
#define QKVN 6144
#define MROWS 4096
#define ATT_SCALE 0.08838834764831845f
#define QSCALE (0.08838834764831845f * 1.4426950408889634f)
#define ROPE_C (-0.2076205059304601f)   // -log2(10000)/64

DEVI void gload_lds16(const bf16* g, bf16* l) {
  __builtin_amdgcn_global_load_lds(
      (__attribute__((address_space(1))) void*)(g),
      (__attribute__((address_space(3))) void*)(l), 16, 0, 0);
}

// ---------------- merged prep: 4x weight transpose + hidden f32->bf16 ----------------
// Block ranges (block-uniform branch): [0,4096) wq, [4096,5120) wk, [5120,6144) wv,
// [6144,10240) wo, [10240,26624) h2b. Bodies identical to the proven standalone kernels.
DEVI void wtrans_body(const float* in, bf16* out, int K, int N, int bx, int by,
                      float (*t)[65]) {
  int n0 = bx * 64, k0 = by * 64;
  int tid = threadIdx.x;
  int tx = tid & 15, ty = tid >> 4;   // 16 x 16
#pragma unroll
  for (int rr = 0; rr < 4; ++rr) {
    int k = ty * 4 + rr;
    float4 v = *(const float4*)(in + (long)(k0 + k) * N + n0 + tx * 4);
    t[k][tx * 4 + 0] = v.x; t[k][tx * 4 + 1] = v.y;
    t[k][tx * 4 + 2] = v.z; t[k][tx * 4 + 3] = v.w;
  }
  __syncthreads();
  int kc = tid & 7, nn = tid >> 3;    // 8 k-chunks x 32 n-rows
#pragma unroll
  for (int pp = 0; pp < 2; ++pp) {
    int n = nn + pp * 32;
    bf16x8 o;
#pragma unroll
    for (int j = 0; j < 8; ++j) o[j] = (bf16)t[kc * 8 + j][n];
    *(bf16x8*)(out + (long)(n0 + n) * K + k0 + kc * 8) = o;
  }
}

__global__ void prep_kernel(const float* __restrict__ hidden,
                            const float* __restrict__ wq, const float* __restrict__ wk,
                            const float* __restrict__ wv, const float* __restrict__ wo,
                            bf16* __restrict__ h_bf, bf16* __restrict__ wqkvT,
                            bf16* __restrict__ woT) {
  __shared__ float t[64][65];
  int bid = blockIdx.x;
  if (bid < 4096) {                       // wq: 64x64 tiles, (HID,HID)
    wtrans_body(wq, wqkvT, HID, HID, bid & 63, bid >> 6, t);
  } else if (bid < 5120) {                // wk: 16x64 tiles, (HID,1024)
    int j = bid - 4096;
    wtrans_body(wk, wqkvT + (long)4096 * HID, HID, 1024, j & 15, j >> 4, t);
  } else if (bid < 6144) {                // wv
    int j = bid - 5120;
    wtrans_body(wv, wqkvT + (long)5120 * HID, HID, 1024, j & 15, j >> 4, t);
  } else if (bid < 10240) {               // wo
    int j = bid - 6144;
    wtrans_body(wo, woT, HID, HID, j & 63, j >> 6, t);
  } else {                                // h2b: 16384 blocks x 1024 elems
    long i = ((long)(bid - 10240) * 256 + threadIdx.x) * 4;
    float4 v = *(const float4*)(hidden + i);
    bf16x4 o;
    o[0] = (bf16)v.x; o[1] = (bf16)v.y; o[2] = (bf16)v.z; o[3] = (bf16)v.w;
    *(bf16x4*)(h_bf + i) = o;
  }
}

// ---------------- merged ropek + vtrans ----------------
// [0,1024) ropek (MROWS*8*8 threads), [1024,5120) vtrans (64 x 4 x 16 tiles).
__global__ void ropevtrans_kernel(bf16* __restrict__ qkv, const int* __restrict__ pos,
                                  bf16* __restrict__ vt) {
  __shared__ bf16 t[32][33];
  int bid = blockIdx.x;
  if (bid < 1024) {
    long tt = (long)bid * 256 + threadIdx.x;
    int d8 = (int)(tt & 7) * 8;
    long u = tt >> 3;
    int hh = (int)(u % 8);
    int row = (int)(u / 8);
    float p = (float)pos[row];
    bf16* base = qkv + (long)row * QKVN + 4096 + hh * HD + d8;
    bf16x8 x1v = *(const bf16x8*)(base);
    bf16x8 x2v = *(const bf16x8*)(base + 64);
    bf16x8 o1, o2;
#pragma unroll
    for (int j = 0; j < 8; ++j) {
      float ang = p * exp2f((float)(d8 + j) * ROPE_C);
      float sn, cs;
      __sincosf(ang, &sn, &cs);
      float x1 = (float)x1v[j], x2 = (float)x2v[j];
      o1[j] = (bf16)(x1 * cs - x2 * sn);
      o2[j] = (bf16)(x2 * cs + x1 * sn);
    }
    *(bf16x8*)(base) = o1;
    *(bf16x8*)(base + 64) = o2;
  } else {
    int j = bid - 1024;                   // 64 s-tiles x 4 d-tiles x 16 bk
    int sxt = j & 63, dyt = (j >> 6) & 3, bk = j >> 8;
    int s0 = sxt * 32, d0 = dyt * 32;
    int b = bk >> 3, kvh = bk & 7;
    int tid = threadIdx.x;
    int tx = tid & 31, ty = tid >> 5;     // (32,8)
#pragma unroll
    for (int r = 0; r < 4; ++r) {
      int s = ty + r * 8;
      t[s][tx] = qkv[(long)(b * SEQ + s0 + s) * QKVN + 5120 + kvh * HD + d0 + tx];
    }
    __syncthreads();
#pragma unroll
    for (int r = 0; r < 4; ++r) {
      int d = ty + r * 8;
      vt[((long)bk * HD + d0 + d) * SEQ + s0 + tx] = t[tx][d];
    }
  }
}

// ---------------- ring-3 GEMM (proven, GEMM1): C = A x BT^T ----------------
template <typename OutT>
__global__ __launch_bounds__(512, 2)
void gemm256(const bf16* __restrict__ A, const bf16* __restrict__ BT,
             OutT* __restrict__ C, int M, int N, int K) {
  extern __shared__ __align__(16) bf16 lds[];
  const int tid = threadIdx.x;
  const int lane = tid & 63, wave = tid >> 6;
  const int wm = wave >> 1, wn = wave & 1;
  const int l16 = lane & 15, lhi = lane >> 4;
  const int nwg = gridDim.x * gridDim.y;
  const int bid = blockIdx.y * gridDim.x + blockIdx.x;
  const int cpx = nwg >> 3;
  const int swz = (bid & 7) * cpx + (bid >> 3);
  const int bx = swz % gridDim.x, by = swz / gridDim.x;
  const long bm0 = (long)by * 256, bn0 = (long)bx * 128;

  const int srow8 = lane >> 3;
  const int scol = (lane & 7) ^ srow8;

  const int NT = K >> 6;
  f32x4 acc[4][4] = {};

  auto stage = [&](int slot, int t) {
    const long k0 = (long)t << 6;
    bf16* dst = lds + slot * 24576;
#pragma unroll
    for (int i = 0; i < 4; ++i) {
      int r = (wave * 4 + i) * 8 + srow8;
      gload_lds16(A + (bm0 + r) * K + k0 + scol * 8,
                  dst + (wave * 4 + i) * 512 + lane * 8);
    }
#pragma unroll
    for (int i = 0; i < 2; ++i) {
      int r = (wave * 2 + i) * 8 + srow8;
      gload_lds16(BT + (bn0 + r) * K + k0 + scol * 8,
                  dst + 16384 + (wave * 2 + i) * 512 + lane * 8);
    }
  };

  stage(0, 0);
  stage(1, 1);

  for (int t = 0; t < NT; ++t) {
    asm volatile("s_waitcnt vmcnt(6)" ::: "memory");
    __builtin_amdgcn_s_barrier();
    __builtin_amdgcn_sched_barrier(0);
    const int nxt = (t + 2 < NT) ? t + 2 : NT - 1;
    stage((t + 2) % 3, nxt);
    const bf16* As = lds + (t % 3) * 24576;
    const bf16* Bs = As + 16384;
#pragma unroll
    for (int kk = 0; kk < 2; ++kk) {
      bf16x8 af[4], bw[4];
#pragma unroll
      for (int i = 0; i < 4; ++i) {
        int ar = wm * 64 + i * 16 + l16;
        af[i] = *(const bf16x8*)(As + ar * 64 + (((kk * 4 + lhi) ^ (ar & 7))) * 8);
        int br = wn * 64 + i * 16 + l16;
        bw[i] = *(const bf16x8*)(Bs + br * 64 + (((kk * 4 + lhi) ^ (br & 7))) * 8);
      }
      __builtin_amdgcn_s_setprio(1);
#pragma unroll
      for (int i = 0; i < 4; ++i)
#pragma unroll
        for (int j = 0; j < 4; ++j)
          acc[i][j] = __builtin_amdgcn_mfma_f32_16x16x32_bf16(af[i], bw[j], acc[i][j], 0, 0, 0);
      __builtin_amdgcn_s_setprio(0);
    }
  }
  asm volatile("s_waitcnt vmcnt(0)" ::: "memory");
#pragma unroll
  for (int i = 0; i < 4; ++i)
#pragma unroll
    for (int r = 0; r < 4; ++r) {
      long grow = bm0 + wm * 64 + i * 16 + lhi * 4 + r;
#pragma unroll
      for (int j = 0; j < 4; ++j) {
        long gcol = bn0 + wn * 64 + j * 16 + l16;
        C[grow * N + gcol] = (OutT)acc[i][j][r];
      }
    }
}

// ---------------- 8-phase GEMM v2 (GEMM2: 4096^2, grid 256 = exactly 1/CU) ----------------
template <typename OutT>
__global__ __launch_bounds__(512, 2)
void gemm8p(const bf16* __restrict__ A, const bf16* __restrict__ BT,
            OutT* __restrict__ C, int M, int N, int K) {
  extern __shared__ __align__(16) bf16 lds[];
  const int tid = threadIdx.x;
  const int lane = tid & 63, wave = tid >> 6;
  const int wm = wave >> 2, wn = wave & 3;   // 2M x 4N
  const int l16 = lane & 15, lhi = lane >> 4;
  const int nwg = gridDim.x * gridDim.y;
  const int bid = blockIdx.y * gridDim.x + blockIdx.x;
  const int cpx = nwg >> 3;
  const int swz = (bid & 7) * cpx + (bid >> 3);
  const int bx = swz % gridDim.x, by = swz / gridDim.x;
  const long bm0 = (long)by * 256, bn0 = (long)bx * 256;

  bf16* Alds = lds;              // [2 buf][2 half][128][64]
  bf16* Blds = lds + 32768;
  const int NT = K >> 6;

  f32x4 acc[8][4] = {};

  auto stageH = [&](const bf16* src, long row0, long k0, bf16* dst) {
#pragma unroll
    for (int j = 0; j < 2; ++j) {
      int r = j * 64 + (tid >> 3);
      int sc = (tid & 7) ^ (r & 7);
      gload_lds16(src + (row0 + r) * (long)K + k0 + sc * 8,
                  dst + j * 4096 + tid * 8);
    }
  };

  stageH(A, bm0, 0, Alds);
  stageH(A, bm0 + 128, 0, Alds + 8192);
  stageH(BT, bn0, 0, Blds);
  stageH(BT, bn0 + 128, 0, Blds + 8192);
  {
    long k1p = (NT > 1) ? 64 : 0;
    stageH(BT, bn0, k1p, Blds + 16384);
    stageH(BT, bn0 + 128, k1p, Blds + 24576);
    stageH(A, bm0, k1p, Alds + 16384);
  }
  asm volatile("s_waitcnt vmcnt(6)" ::: "memory");
  __builtin_amdgcn_s_barrier();

  const int arow0 = wm * 128 + l16;
  const int brow0 = wn * 64 + l16;

  for (int t = 0; t < NT; ++t) {
    const bf16* Ab = Alds + (t & 1) * 16384;
    const bf16* Bb = Blds + (t & 1) * 16384;
    bf16* Aopp = Alds + ((t + 1) & 1) * 16384;
    bf16* Asame = Alds + (t & 1) * 16384;
    bf16* Bsame = Blds + (t & 1) * 16384;
    const long k1 = (long)((t + 1 < NT) ? t + 1 : NT - 1) << 6;
    const long k2 = (long)((t + 2 < NT) ? t + 2 : NT - 1) << 6;

    bf16x8 a0[4][2], a1[4][2], b0[2][2], b1[2][2];
    // phase 0: reads a0+b0; MFMA q(mh0,np0)
#pragma unroll
    for (int i = 0; i < 4; ++i) {
      int mr = arow0 + i * 16;
#pragma unroll
      for (int kk = 0; kk < 2; ++kk)
        a0[i][kk] = *(const bf16x8*)(Ab + mr * 64 + (((kk * 4 + lhi) ^ (mr & 7))) * 8);
    }
#pragma unroll
    for (int n = 0; n < 2; ++n) {
      int br = brow0 + n * 16;
#pragma unroll
      for (int kk = 0; kk < 2; ++kk)
        b0[n][kk] = *(const bf16x8*)(Bb + br * 64 + (((kk * 4 + lhi) ^ (br & 7))) * 8);
    }
    __builtin_amdgcn_s_barrier();
    asm volatile("s_waitcnt lgkmcnt(0)" ::: "memory");
    __builtin_amdgcn_sched_barrier(0);
    __builtin_amdgcn_s_setprio(1);
#pragma unroll
    for (int i = 0; i < 4; ++i)
#pragma unroll
      for (int n = 0; n < 2; ++n)
#pragma unroll
        for (int kk = 0; kk < 2; ++kk)
          acc[i][n] = __builtin_amdgcn_mfma_f32_16x16x32_bf16(a0[i][kk], b0[n][kk], acc[i][n], 0, 0, 0);
    __builtin_amdgcn_s_setprio(0);
    __builtin_amdgcn_s_barrier();
    // phase 1: reads a1; stage A-hi(t+1); MFMA q(mh1,np0)
#pragma unroll
    for (int i = 0; i < 4; ++i) {
      int mr = arow0 + 64 + i * 16;
#pragma unroll
      for (int kk = 0; kk < 2; ++kk)
        a1[i][kk] = *(const bf16x8*)(Ab + mr * 64 + (((kk * 4 + lhi) ^ (mr & 7))) * 8);
    }
    stageH(A, bm0 + 128, k1, Aopp + 8192);
    __builtin_amdgcn_s_barrier();
    asm volatile("s_waitcnt lgkmcnt(0)" ::: "memory");
    __builtin_amdgcn_sched_barrier(0);
    __builtin_amdgcn_s_setprio(1);
#pragma unroll
    for (int i = 0; i < 4; ++i)
#pragma unroll
      for (int n = 0; n < 2; ++n)
#pragma unroll
        for (int kk = 0; kk < 2; ++kk)
          acc[4 + i][n] = __builtin_amdgcn_mfma_f32_16x16x32_bf16(a1[i][kk], b0[n][kk], acc[4 + i][n], 0, 0, 0);
    __builtin_amdgcn_s_setprio(0);
    __builtin_amdgcn_s_barrier();
    // phase 2: reads b1; stage A-lo(t+2); MFMA q(mh1,np1)
#pragma unroll
    for (int n = 0; n < 2; ++n) {
      int br = brow0 + (n + 2) * 16;
#pragma unroll
      for (int kk = 0; kk < 2; ++kk)
        b1[n][kk] = *(const bf16x8*)(Bb + br * 64 + (((kk * 4 + lhi) ^ (br & 7))) * 8);
    }
    stageH(A, bm0, k2, Asame);
    __builtin_amdgcn_s_barrier();
    asm volatile("s_waitcnt lgkmcnt(0)" ::: "memory");
    __builtin_amdgcn_sched_barrier(0);
    __builtin_amdgcn_s_setprio(1);
#pragma unroll
    for (int i = 0; i < 4; ++i)
#pragma unroll
      for (int n = 0; n < 2; ++n)
#pragma unroll
        for (int kk = 0; kk < 2; ++kk)
          acc[4 + i][n + 2] = __builtin_amdgcn_mfma_f32_16x16x32_bf16(a1[i][kk], b1[n][kk], acc[4 + i][n + 2], 0, 0, 0);
    __builtin_amdgcn_s_setprio(0);
    __builtin_amdgcn_s_barrier();
    // phase 3: stage B-lo+B-hi(t+2); MFMA q(mh0,np1); vmcnt(6)
    stageH(BT, bn0, k2, Bsame);
    stageH(BT, bn0 + 128, k2, Bsame + 8192);
    __builtin_amdgcn_s_barrier();
    __builtin_amdgcn_s_setprio(1);
#pragma unroll
    for (int i = 0; i < 4; ++i)
#pragma unroll
      for (int n = 0; n < 2; ++n)
#pragma unroll
        for (int kk = 0; kk < 2; ++kk)
          acc[i][n + 2] = __builtin_amdgcn_mfma_f32_16x16x32_bf16(a0[i][kk], b1[n][kk], acc[i][n + 2], 0, 0, 0);
    __builtin_amdgcn_s_setprio(0);
    asm volatile("s_waitcnt vmcnt(6)" ::: "memory");
    __builtin_amdgcn_s_barrier();
  }
  asm volatile("s_waitcnt vmcnt(0)" ::: "memory");
#pragma unroll
  for (int mi = 0; mi < 8; ++mi)
#pragma unroll
    for (int r = 0; r < 4; ++r) {
      long grow = bm0 + wm * 128 + mi * 16 + lhi * 4 + r;
#pragma unroll
      for (int n = 0; n < 4; ++n) {
        long gcol = bn0 + wn * 64 + n * 16 + l16;
        C[grow * N + gcol] = (OutT)acc[mi][n][r];
      }
    }
}

// ---------------- flash attention: balanced pairs + fused Q-RoPE + mask hoist (proven) ---
__global__ __launch_bounds__(512, 4)
void attn_kernel(const bf16* __restrict__ qkv, const bf16* __restrict__ vt,
                 const int* __restrict__ pos, bf16* __restrict__ out) {
  extern __shared__ __align__(16) bf16 smem[];
  const int pi = blockIdx.x, h = blockIdx.y, b = blockIdx.z;
  const int kvh = h >> 2;
  const int tid = threadIdx.x, lane = tid & 63, wave = tid >> 6;
  const int l16 = lane & 15, lhi = lane >> 4;
  const int kloc = lhi * 4;
  bf16* Pw = smem + 32768 + wave * 1024;

  const bf16* kpan = qkv + (long)(b * SEQ) * QKVN + 4096 + kvh * HD;
  const bf16* vpan = vt + (long)(b * NKVH + kvh) * HD * SEQ;

  auto stageKV = [&](int buf, int step) {
    const int kv0 = step * 64;
    bf16* kd = smem + buf * 8192;
    bf16* vd = smem + 16384 + buf * 8192;
#pragma unroll
    for (int i = 0; i < 2; ++i) {
      int kr = wave * 8 + i * 4 + lhi;
      gload_lds16(kpan + (long)(kv0 + kr) * QKVN + (l16 ^ (kr & 7)) * 8,
                  kd + (wave * 8 + i * 4) * 128);
      int vr = wave * 16 + i * 8 + (lane >> 3);
      gload_lds16(vpan + (long)vr * SEQ + kv0 + ((lane & 7) ^ (vr & 7)) * 8,
                  vd + (wave * 16 + i * 8) * 64);
    }
  };

  auto process_chunk = [&](int q0, int nsteps) {
    const int qrow = q0 + wave * 16 + l16;
    float p = (float)pos[b * SEQ + qrow];
    const bf16* qb = qkv + (long)(b * SEQ + qrow) * QKVN + h * HD + lhi * 8;
    bf16x8 raw[4];
#pragma unroll
    for (int di = 0; di < 4; ++di) raw[di] = *(const bf16x8*)(qb + di * 32);
    bf16x8 qf[4];
#pragma unroll
    for (int pr = 0; pr < 2; ++pr)
#pragma unroll
      for (int j = 0; j < 8; ++j) {
        int d = lhi * 8 + pr * 32 + j;
        float ang = p * exp2f((float)d * ROPE_C);
        float sn, cs;
        __sincosf(ang, &sn, &cs);
        float x1 = (float)raw[pr][j], x2 = (float)raw[pr + 2][j];
        qf[pr][j] = (bf16)((x1 * cs - x2 * sn) * QSCALE);
        qf[pr + 2][j] = (bf16)((x2 * cs + x1 * sn) * QSCALE);
      }

    f32x4 oacc[8] = {};
    float m_run = -1e30f, l_run = 0.f;
    const int qg = qrow;
    const int qwmin = q0 + wave * 16;

    stageKV(0, 0);
    __syncthreads();

    for (int step = 0; step < nsteps; ++step) {
      const int kv0 = step * 64;
      const int cur = step & 1;
      if (step + 1 < nsteps) stageKV(cur ^ 1, step + 1);
      const bf16* Kc = smem + cur * 8192;
      const bf16* Vc = smem + 16384 + cur * 8192;

      f32x4 s[4];
      __builtin_amdgcn_s_setprio(1);
#pragma unroll
      for (int c = 0; c < 4; ++c) {
        s[c] = (f32x4){0.f, 0.f, 0.f, 0.f};
        int kr = c * 16 + l16;
#pragma unroll
        for (int di = 0; di < 4; ++di) {
          bf16x8 kf = *(const bf16x8*)(Kc + kr * 128 + (((di * 4 + lhi) ^ (kr & 7))) * 8);
          s[c] = __builtin_amdgcn_mfma_f32_16x16x32_bf16(kf, qf[di], s[c], 0, 0, 0);
        }
      }
      __builtin_amdgcn_s_setprio(0);
      if (kv0 + 63 > qwmin) {
#pragma unroll
        for (int c = 0; c < 4; ++c)
#pragma unroll
          for (int r = 0; r < 4; ++r) {
            int kcol = kv0 + c * 16 + kloc + r;
            if (kcol > qg) s[c][r] = -1e30f;
          }
      }
      float mloc = s[0][0];
#pragma unroll
      for (int c = 0; c < 4; ++c)
#pragma unroll
        for (int r = 0; r < 4; ++r) mloc = fmaxf(mloc, s[c][r]);
      mloc = fmaxf(mloc, __shfl_xor(mloc, 16, 64));
      mloc = fmaxf(mloc, __shfl_xor(mloc, 32, 64));
      bool skip = __all(mloc - m_run <= 8.0f);
      float alpha = 1.f;
      if (!skip) {
        float mn = fmaxf(m_run, mloc);
        alpha = exp2f(m_run - mn);
        m_run = mn;
      }
      float sm = 0.f;
      bf16x4 pb[4];
#pragma unroll
      for (int c = 0; c < 4; ++c)
#pragma unroll
        for (int r = 0; r < 4; ++r) {
          float pv = exp2f(s[c][r] - m_run);
          sm += pv;
          pb[c][r] = (bf16)pv;
        }
      sm += __shfl_xor(sm, 16, 64);
      sm += __shfl_xor(sm, 32, 64);
      l_run = l_run * alpha + sm;
#pragma unroll
      for (int c = 0; c < 4; ++c) {
        int sl = (c * 2 + (lhi >> 1)) ^ (l16 & 7);
        *(bf16x4*)(Pw + l16 * 64 + sl * 8 + (lhi & 1) * 4) = pb[c];
      }
      if (!skip) {
        float a_o[4];
#pragma unroll
        for (int r = 0; r < 4; ++r) a_o[r] = __shfl(alpha, kloc + r, 64);
#pragma unroll
        for (int dj = 0; dj < 8; ++dj)
#pragma unroll
          for (int r = 0; r < 4; ++r) oacc[dj][r] *= a_o[r];
      }
      __builtin_amdgcn_s_setprio(1);
#pragma unroll
      for (int kh = 0; kh < 2; ++kh) {
        bf16x8 pf = *(const bf16x8*)(Pw + l16 * 64 + (((kh * 4 + lhi) ^ (l16 & 7))) * 8);
#pragma unroll
        for (int dj = 0; dj < 8; ++dj) {
          int vr = dj * 16 + l16;
          bf16x8 vf = *(const bf16x8*)(Vc + vr * 64 + (((kh * 4 + lhi) ^ (vr & 7))) * 8);
          oacc[dj] = __builtin_amdgcn_mfma_f32_16x16x32_bf16(pf, vf, oacc[dj], 0, 0, 0);
        }
      }
      __builtin_amdgcn_s_setprio(0);
      __syncthreads();
    }
    float linv[4];
#pragma unroll
    for (int r = 0; r < 4; ++r) linv[r] = 1.f / __shfl(l_run, kloc + r, 64);
#pragma unroll
    for (int r = 0; r < 4; ++r) {
      long orow = (long)(b * SEQ + q0 + wave * 16 + lhi * 4 + r);
#pragma unroll
      for (int dj = 0; dj < 8; ++dj)
        out[orow * (NH * HD) + h * HD + dj * 16 + l16] = (bf16)(oacc[dj][r] * linv[r]);
    }
  };

  process_chunk(pi * 128, 2 * pi + 2);
  process_chunk((15 - pi) * 128, 32 - 2 * pi);
}

extern "C" void kernel_launch(void* const* d_in, const int* in_sizes, int n_in,
                              void* d_out, int out_size, void* d_ws, size_t ws_size,
                              hipStream_t stream) {
  const int* positions = (const int*)d_in[0];
  const float* hidden = (const float*)d_in[1];
  const float* wq = (const float*)d_in[2];
  const float* wk = (const float*)d_in[3];
  const float* wv = (const float*)d_in[4];
  const float* wo = (const float*)d_in[5];
  float* out = (float*)d_out;
  char* ws = (char*)d_ws;

  const size_t SZ_H = (size_t)MROWS * HID * 2;
  const size_t SZ_WQKV = (size_t)QKVN * HID * 2;
  const size_t SZ_WO = (size_t)HID * HID * 2;
  bf16* h_bf = (bf16*)(ws);
  bf16* wqkvT = (bf16*)(ws + SZ_H);
  bf16* woT = (bf16*)(ws + SZ_H + SZ_WQKV);
  bf16* qkv = (bf16*)(ws + SZ_H + SZ_WQKV + SZ_WO);
  bf16* attn = h_bf;
  bf16* vtbuf = wqkvT;

  const int G8P_SMEM = 131072;
  const int R3_SMEM = 3 * 24576 * 2;
  const int ATTN_SMEM = 40960 * 2;
  auto* g1 = gemm256<bf16>;
  auto* g2 = gemm8p<float>;
  hipFuncSetAttribute(reinterpret_cast<const void*>(g1),
                      hipFuncAttributeMaxDynamicSharedMemorySize, R3_SMEM);
  hipFuncSetAttribute(reinterpret_cast<const void*>(g2),
                      hipFuncAttributeMaxDynamicSharedMemorySize, G8P_SMEM);
  hipFuncSetAttribute(reinterpret_cast<const void*>(attn_kernel),
                      hipFuncAttributeMaxDynamicSharedMemorySize, ATTN_SMEM);

  // merged prep: 4x wtrans (10240 blocks) + h2b (16384 blocks)
  prep_kernel<<<26624, 256, 0, stream>>>(hidden, wq, wk, wv, wo, h_bf, wqkvT, woT);
  gemm256<bf16><<<dim3(QKVN / 128, MROWS / 256), 512, R3_SMEM, stream>>>(h_bf, wqkvT, qkv, MROWS, QKVN, HID);
  // merged ropek (1024) + vtrans (4096)
  ropevtrans_kernel<<<5120, 256, 0, stream>>>(qkv, positions, vtbuf);
  attn_kernel<<<dim3(8, NH, BATCH), 512, ATTN_SMEM, stream>>>(qkv, vtbuf, positions, attn);
  gemm8p<float><<<dim3(HID / 256, MROWS / 256), 512, G8P_SMEM, stream>>>(attn, woT, out, MROWS, HID, HID);
}